// Round 6
// baseline (981.955 us; speedup 1.0000x reference)
//
#include <hip/hip_runtime.h>
#include <hip/hip_bf16.h>
#include <cstdint>

// MultiHeadAttention w/ sparsemax: B=2, S=2048, D=1024, H=16, DK=64
#define S_LEN  2048
#define DMODEL 1024
#define NHEAD  16
#define M_ROWS 4096                       // B*S

typedef __attribute__((ext_vector_type(8))) short bf16x8;   // MFMA A/B frag (8 bf16)
typedef __attribute__((ext_vector_type(4))) float f32x4;    // MFMA C/D frag

__device__ __forceinline__ unsigned short f2bf(float f) {
    __hip_bfloat16 h = __float2bfloat16(f);
    return __builtin_bit_cast(unsigned short, h);
}
__device__ __forceinline__ float bf2f(unsigned short u) {
    return __builtin_bit_cast(float, (unsigned)u << 16);
}
__device__ __forceinline__ uint4 pack8(float4 a, float4 b) {
    uint4 u;
    u.x = ((unsigned)f2bf(a.y) << 16) | f2bf(a.x);
    u.y = ((unsigned)f2bf(a.w) << 16) | f2bf(a.z);
    u.z = ((unsigned)f2bf(b.y) << 16) | f2bf(b.x);
    u.w = ((unsigned)f2bf(b.w) << 16) | f2bf(b.z);
    return u;
}

// ---------------------------------------------------------------- wave reduce
__device__ __forceinline__ float wave_sum64(float v) {
    v += __shfl_xor(v, 32, 64); v += __shfl_xor(v, 16, 64);
    v += __shfl_xor(v, 8, 64);  v += __shfl_xor(v, 4, 64);
    v += __shfl_xor(v, 2, 64);  v += __shfl_xor(v, 1, 64);
    return v;
}
__device__ __forceinline__ float wave_max64(float v) {
    v = fmaxf(v, __shfl_xor(v, 32, 64)); v = fmaxf(v, __shfl_xor(v, 16, 64));
    v = fmaxf(v, __shfl_xor(v, 8, 64));  v = fmaxf(v, __shfl_xor(v, 4, 64));
    v = fmaxf(v, __shfl_xor(v, 2, 64));  v = fmaxf(v, __shfl_xor(v, 1, 64));
    return v;
}
__device__ __forceinline__ int lanes_below(unsigned long long m) {
    return __builtin_amdgcn_mbcnt_hi((unsigned)(m >> 32),
           __builtin_amdgcn_mbcnt_lo((unsigned)m, 0));
}

// ----------------------- one-shot fp32 -> bf16 conversion (inputs + weights)
// Outputs land in the attn region of d_out (scratch whose lifetime ends when
// attn_fused starts overwriting it). Same f2bf RNE as the old inline pack8,
// so Q/K/V results are bit-identical to previous rounds.
__global__ __launch_bounds__(256)
void cvt_bf16(const float* __restrict__ xq, const float* __restrict__ xk,
              const float* __restrict__ xv,
              const float* __restrict__ Wq, const float* __restrict__ Wk,
              const float* __restrict__ Wv,
              unsigned short* __restrict__ oXq, unsigned short* __restrict__ oXk,
              unsigned short* __restrict__ oXv,
              unsigned short* __restrict__ oWq, unsigned short* __restrict__ oWk,
              unsigned short* __restrict__ oWv) {
    const int y = blockIdx.y;
    const float* src = (y == 0) ? xq : (y == 1) ? xk : (y == 2) ? xv
                     : (y == 3) ? Wq : (y == 4) ? Wk : Wv;
    unsigned short* dst = (y == 0) ? oXq : (y == 1) ? oXk : (y == 2) ? oXv
                        : (y == 3) ? oWq : (y == 4) ? oWk : oWv;
    const int n = (y < 3) ? (M_ROWS * DMODEL) : (DMODEL * DMODEL);
    const int stride = gridDim.x * blockDim.x * 8;
    for (int i = (blockIdx.x * blockDim.x + threadIdx.x) * 8; i < n; i += stride) {
        float4 a = *(const float4*)(src + i);
        float4 b = *(const float4*)(src + i + 4);
        *(uint4*)(dst + i) = pack8(a, b);
    }
}

// ------------------------------------- qkv: C = A@W^T + b (bf16 in, bf16 MFMA)
// A[4096,1024] bf16, W[1024,1024] bf16 (NT; both pre-converted by cvt_bf16).
// Output row-major bf16 [B,S,DMODEL] via LDS-transpose epilogue (16B stores).
// Q output (which==0) is pre-scaled by 0.125 (= 1/sqrt(DK)).
__global__ __launch_bounds__(256)
void qkv_gemm(const unsigned short* __restrict__ Xq, const unsigned short* __restrict__ Xk,
              const unsigned short* __restrict__ Xv,
              const unsigned short* __restrict__ Wqb, const unsigned short* __restrict__ Wkb,
              const unsigned short* __restrict__ Wvb,
              const float* __restrict__ bq, const float* __restrict__ bk,
              const float* __restrict__ bv,
              unsigned short* __restrict__ Q_bf, unsigned short* __restrict__ K_bf,
              unsigned short* __restrict__ V_bf) {
    const int which = blockIdx.z;
    const unsigned short* A = (which == 0) ? Xq : (which == 1) ? Xk : Xv;
    const unsigned short* W = (which == 0) ? Wqb : (which == 1) ? Wkb : Wvb;
    const float* bias  = (which == 0) ? bq : (which == 1) ? bk : bv;
    unsigned short* dst = (which == 0) ? Q_bf : (which == 1) ? K_bf : V_bf;
    const float qscale = (which == 0) ? 0.125f : 1.0f;

    const int row0 = blockIdx.x * 128;
    const int col0 = blockIdx.y * 128;

    __shared__ unsigned short SMEM[10240];    // As(5120) + Bs(5120); epilogue aliases
    unsigned short* As = SMEM;                // stride 40 bf16 (2-way free)
    unsigned short* Bs = SMEM + 5120;

    const int t = threadIdx.x;
    const int wid = t >> 6, lane = t & 63;
    const int wm = wid >> 1, wn = wid & 1;
    const int l = lane & 15, quad = lane >> 4;

    f32x4 acc[4][4];
#pragma unroll
    for (int i = 0; i < 4; ++i)
#pragma unroll
        for (int j = 0; j < 4; ++j) {
            float b_ = bias[col0 + wn * 64 + j * 16 + l];
            acc[i][j] = (f32x4){ b_, b_, b_, b_ };
        }

    for (int k0 = 0; k0 < DMODEL; k0 += 32) {
        uint4 ar[2], br[2];
#pragma unroll
        for (int i = 0; i < 2; ++i) {
            const int c = t + i * 256, r = c >> 2, q = (c & 3) * 8;
            ar[i] = *(const uint4*)(A + (size_t)(row0 + r) * DMODEL + k0 + q);
            br[i] = *(const uint4*)(W + (size_t)(col0 + r) * DMODEL + k0 + q);
        }
        __syncthreads();
#pragma unroll
        for (int i = 0; i < 2; ++i) {
            const int c = t + i * 256, r = c >> 2, q = (c & 3) * 8;
            *(uint4*)&As[r * 40 + q] = ar[i];
            *(uint4*)&Bs[r * 40 + q] = br[i];
        }
        __syncthreads();
        bf16x8 a[4], b[4];
#pragma unroll
        for (int i = 0; i < 4; ++i)
            a[i] = *(const bf16x8*)&As[(wm * 64 + i * 16 + l) * 40 + quad * 8];
#pragma unroll
        for (int j = 0; j < 4; ++j)
            b[j] = *(const bf16x8*)&Bs[(wn * 64 + j * 16 + l) * 40 + quad * 8];
#pragma unroll
        for (int i = 0; i < 4; ++i)
#pragma unroll
            for (int j = 0; j < 4; ++j)
                acc[i][j] = __builtin_amdgcn_mfma_f32_16x16x32_bf16(a[i], b[j], acc[i][j], 0, 0, 0);
    }

    // ---- epilogue: acc -> LDS (bf16, stride 72 = 16B-aligned rows) -> uint4 stores
    __syncthreads();
    unsigned short* Cs = SMEM;                // 128*72 = 9216 <= 10240
#pragma unroll 1
    for (int jh = 0; jh < 2; ++jh) {
        if (wn == jh) {
#pragma unroll
            for (int i = 0; i < 4; ++i)
#pragma unroll
                for (int j = 0; j < 4; ++j)
#pragma unroll
                    for (int r = 0; r < 4; ++r)
                        Cs[(wm * 64 + i * 16 + quad * 4 + r) * 72 + j * 16 + l] =
                            f2bf(acc[i][j][r] * qscale);
        }
        __syncthreads();
#pragma unroll
        for (int it = 0; it < 4; ++it) {
            const int idx = t + it * 256;           // 0..1023
            const int row = idx >> 3, c8 = (idx & 7) * 8;
            *(uint4*)(dst + (size_t)(row0 + row) * DMODEL + col0 + jh * 64 + c8) =
                *(const uint4*)&Cs[row * 72 + c8];
        }
        __syncthreads();
    }
}

// ------------------------- fused logits + sparsemax + sparse PV -------------------------
// Block = 8 query rows x 2048 cols of one (b,h); 8 waves (512 thr), wave owns row.
// QK^T in 4 column-quarters through a 16 KB LDS transpose region -> z[32]/lane.
// Candidates (z > max-1) compacted once; Newton on candidates (exact fixpoint);
// SUPPORT-only re-compaction from registers (p = z - tau stored directly);
// 4-deep prefetched V gather. No __threadfence_block: same-wave LDS ops are
// in-order, and the old fence forced vmcnt(0) against the attn store burst.
__global__ __launch_bounds__(512, 6)
void attn_fused(const unsigned short* __restrict__ Q_bf,
                const unsigned short* __restrict__ K_bf,
                const unsigned short* __restrict__ V_bf,
                float* __restrict__ attn,
                unsigned short* __restrict__ AO_bf) {
    const int t = threadIdx.x;
    const int w = t >> 6, lane = t & 63;
    const int l = lane & 15, quad = lane >> 4;
    const int bh = blockIdx.y, b_ = bh >> 4, h = bh & 15;
    const int r0 = blockIdx.x * 8;

    __shared__ uint2 List[8 * 512];    // 32 KB; first 16 KB aliased as transpose buf
    float* LDSf = (float*)List;

    // ---- Q fragments: A rows l&7 -> C rows 0..7 valid (8..15 duplicates)
    const unsigned short* Qp =
        Q_bf + ((size_t)(b_ * S_LEN + r0 + (l & 7))) * DMODEL + h * 64 + quad * 8;
    const bf16x8 a0 = *(const bf16x8*)Qp;
    const bf16x8 a1 = *(const bf16x8*)(Qp + 32);

    float z[32];
    float m = -__builtin_inff();
    // ---- QK^T in 4 column-quarters; wave w covers cols q*512 + [w*64, w*64+64)
#pragma unroll
    for (int q = 0; q < 4; ++q) {
        const unsigned short* Kb =
            K_bf + ((size_t)(b_ * S_LEN + q * 512 + w * 64 + l)) * DMODEL
            + h * 64 + quad * 8;
        f32x4 acc[4];
#pragma unroll
        for (int ct = 0; ct < 4; ++ct) {
            const unsigned short* Kp = Kb + (size_t)(ct * 16) * DMODEL;
            const bf16x8 b0 = *(const bf16x8*)Kp;
            const bf16x8 b1 = *(const bf16x8*)(Kp + 32);
            f32x4 c = {};
            c = __builtin_amdgcn_mfma_f32_16x16x32_bf16(a0, b0, c, 0, 0, 0);
            c = __builtin_amdgcn_mfma_f32_16x16x32_bf16(a1, b1, c, 0, 0, 0);
            acc[ct] = c;                           // Q pre-scaled by 1/8 in qkv
        }
        // transpose: rows = quad*4+r (quads 0,1 hold real rows 0..7)
        if (quad < 2) {
#pragma unroll
            for (int ct = 0; ct < 4; ++ct)
#pragma unroll
                for (int r = 0; r < 4; ++r)
                    LDSf[(quad * 4 + r) * 512 + w * 64 + ct * 16 + l] = acc[ct][r];
        }
        __syncthreads();
#pragma unroll
        for (int j = 0; j < 8; ++j) {
            z[q * 8 + j] = LDSf[w * 512 + j * 64 + lane];
            m = fmaxf(m, z[q * 8 + j]);            // running row max (z hot)
        }
        __syncthreads();
    }

    // ---- row max; candidate threshold thr = m - 1 (tau* >= m-1 always)
    m = wave_max64(m);
    const float thr = m - 1.0f;

    // ---- candidate compaction: (col, z) with z > thr, per-wave list
    uint2* list = List + w * 512;
    int cnt = 0;
#pragma unroll
    for (int jj = 0; jj < 32; ++jj) {
        const float zv = z[jj];
        const unsigned long long mk = __ballot(zv > thr);
        if (zv > thr) {
            const int pos = cnt + lanes_below(mk);
            if (pos < 512)
                list[pos] = (uint2){ (unsigned)((jj >> 3) * 512 + (jj & 7) * 64 + lane),
                                     __builtin_bit_cast(unsigned, zv) };
        }
        cnt += __popcll(mk);
    }

    // ---- Newton waterfilling on candidates (common) or full scan (fallback)
    float tau = thr;
    int scnt = 0;
    if (cnt <= 256) {
        const float NEG = -__builtin_inff();
        const uint2 E0 = list[lane];
        const uint2 E1 = list[64 + lane];
        const uint2 E2 = list[128 + lane];
        const uint2 E3 = list[192 + lane];
        const float zc0 = (lane < cnt)       ? __builtin_bit_cast(float, E0.y) : NEG;
        const float zc1 = (64 + lane < cnt)  ? __builtin_bit_cast(float, E1.y) : NEG;
        const float zc2 = (128 + lane < cnt) ? __builtin_bit_cast(float, E2.y) : NEG;
        const float zc3 = (192 + lane < cnt) ? __builtin_bit_cast(float, E3.y) : NEG;
#pragma unroll 1
        for (int it = 0; it < 12; ++it) {
            float ss = 0.0f, kk = 0.0f;
            if (zc0 > tau) { ss += zc0; kk += 1.0f; }
            if (zc1 > tau) { ss += zc1; kk += 1.0f; }
            if (zc2 > tau) { ss += zc2; kk += 1.0f; }
            if (zc3 > tau) { ss += zc3; kk += 1.0f; }
            ss = wave_sum64(ss); kk = wave_sum64(kk);
            const float tn = (ss - 1.0f) / kk;     // uniform across wave
            if (tn == tau) break;                  // support stabilized -> exact
            tau = tn;
        }
        // ---- support re-compaction from registers: store (col, p=z-tau)
        unsigned long long mk;
        mk = __ballot(zc0 > tau);
        if (zc0 > tau) list[scnt + lanes_below(mk)] =
            (uint2){ E0.x, __builtin_bit_cast(unsigned, zc0 - tau) };
        scnt += __popcll(mk);
        mk = __ballot(zc1 > tau);
        if (zc1 > tau) list[scnt + lanes_below(mk)] =
            (uint2){ E1.x, __builtin_bit_cast(unsigned, zc1 - tau) };
        scnt += __popcll(mk);
        mk = __ballot(zc2 > tau);
        if (zc2 > tau) list[scnt + lanes_below(mk)] =
            (uint2){ E2.x, __builtin_bit_cast(unsigned, zc2 - tau) };
        scnt += __popcll(mk);
        mk = __ballot(zc3 > tau);
        if (zc3 > tau) list[scnt + lanes_below(mk)] =
            (uint2){ E3.x, __builtin_bit_cast(unsigned, zc3 - tau) };
        scnt += __popcll(mk);
    } else {
#pragma unroll 1
        for (int it = 0; it < 8; ++it) {
            float ss = 0.0f, kk = 0.0f;
#pragma unroll
            for (int j = 0; j < 32; ++j)
                if (z[j] > tau) { ss += z[j]; kk += 1.0f; }
            ss = wave_sum64(ss); kk = wave_sum64(kk);
            const float tn = (ss - 1.0f) / kk;
            if (tn == tau) break;
            tau = tn;
        }
        // recompact: support only, store (col, p=z-tau)
#pragma unroll
        for (int jj = 0; jj < 32; ++jj) {
            const float zv = z[jj];
            const unsigned long long mk = __ballot(zv > tau);
            if (zv > tau) {
                const int pos = scnt + lanes_below(mk);
                if (pos < 480)
                    list[pos] = (uint2){ (unsigned)((jj >> 3) * 512 + (jj & 7) * 64 + lane),
                                         __builtin_bit_cast(unsigned, zv - tau) };
            }
            scnt += __popcll(mk);
        }
        if (scnt > 480) scnt = 480;                // exactness cap (never hit here)
    }

    // ---- p = max(z - tau, 0); coalesced nontemporal fp32 attn row store
    float* ap = attn + (size_t)bh * S_LEN * S_LEN + (size_t)(r0 + w) * S_LEN;
#pragma unroll
    for (int jj = 0; jj < 32; ++jj) {
        const float pv = fmaxf(z[jj] - tau, 0.0f);
        __builtin_nontemporal_store(pv, ap + (jj >> 3) * 512 + (jj & 7) * 64 + lane);
    }

    // ---- pad list with 32 zero entries (guard-free 4-deep gather)
    if (lane < 32)
        list[scnt + lane] = (uint2){ 0u, 0u };     // p = 0 -> contributes nothing

    // ---- gather: 32 entries per outer iter (4 x 8-lane subgroups, uint4 each)
    const unsigned short* Vh = V_bf + ((size_t)b_ * S_LEN) * DMODEL + h * 64;
    const int sub = lane >> 3, dbase = (lane & 7) * 8;
    float acc8[8] = {};
    const int gmax4 = (scnt + 31) >> 5;
#pragma unroll 1
    for (int g = 0; g < gmax4; ++g) {
        const int b0 = g * 32 + sub;
        const uint2 e0 = list[b0];
        const uint2 e1 = list[b0 + 8];
        const uint2 e2 = list[b0 + 16];
        const uint2 e3 = list[b0 + 24];
        const uint4 v0 = *(const uint4*)(Vh + (size_t)e0.x * DMODEL + dbase);
        const uint4 v1 = *(const uint4*)(Vh + (size_t)e1.x * DMODEL + dbase);
        const uint4 v2 = *(const uint4*)(Vh + (size_t)e2.x * DMODEL + dbase);
        const uint4 v3 = *(const uint4*)(Vh + (size_t)e3.x * DMODEL + dbase);
        const float p0 = __builtin_bit_cast(float, e0.y);
        const float p1 = __builtin_bit_cast(float, e1.y);
        const float p2 = __builtin_bit_cast(float, e2.y);
        const float p3 = __builtin_bit_cast(float, e3.y);
        acc8[0] += p0 * bf2f((unsigned short)(v0.x & 0xffff));
        acc8[1] += p0 * bf2f((unsigned short)(v0.x >> 16));
        acc8[2] += p0 * bf2f((unsigned short)(v0.y & 0xffff));
        acc8[3] += p0 * bf2f((unsigned short)(v0.y >> 16));
        acc8[4] += p0 * bf2f((unsigned short)(v0.z & 0xffff));
        acc8[5] += p0 * bf2f((unsigned short)(v0.z >> 16));
        acc8[6] += p0 * bf2f((unsigned short)(v0.w & 0xffff));
        acc8[7] += p0 * bf2f((unsigned short)(v0.w >> 16));
        acc8[0] += p1 * bf2f((unsigned short)(v1.x & 0xffff));
        acc8[1] += p1 * bf2f((unsigned short)(v1.x >> 16));
        acc8[2] += p1 * bf2f((unsigned short)(v1.y & 0xffff));
        acc8[3] += p1 * bf2f((unsigned short)(v1.y >> 16));
        acc8[4] += p1 * bf2f((unsigned short)(v1.z & 0xffff));
        acc8[5] += p1 * bf2f((unsigned short)(v1.z >> 16));
        acc8[6] += p1 * bf2f((unsigned short)(v1.w & 0xffff));
        acc8[7] += p1 * bf2f((unsigned short)(v1.w >> 16));
        acc8[0] += p2 * bf2f((unsigned short)(v2.x & 0xffff));
        acc8[1] += p2 * bf2f((unsigned short)(v2.x >> 16));
        acc8[2] += p2 * bf2f((unsigned short)(v2.y & 0xffff));
        acc8[3] += p2 * bf2f((unsigned short)(v2.y >> 16));
        acc8[4] += p2 * bf2f((unsigned short)(v2.z & 0xffff));
        acc8[5] += p2 * bf2f((unsigned short)(v2.z >> 16));
        acc8[6] += p2 * bf2f((unsigned short)(v2.w & 0xffff));
        acc8[7] += p2 * bf2f((unsigned short)(v2.w >> 16));
        acc8[0] += p3 * bf2f((unsigned short)(v3.x & 0xffff));
        acc8[1] += p3 * bf2f((unsigned short)(v3.x >> 16));
        acc8[2] += p3 * bf2f((unsigned short)(v3.y & 0xffff));
        acc8[3] += p3 * bf2f((unsigned short)(v3.y >> 16));
        acc8[4] += p3 * bf2f((unsigned short)(v3.z & 0xffff));
        acc8[5] += p3 * bf2f((unsigned short)(v3.z >> 16));
        acc8[6] += p3 * bf2f((unsigned short)(v3.w & 0xffff));
        acc8[7] += p3 * bf2f((unsigned short)(v3.w >> 16));
    }
    // reduce across the 8 subgroups (stride-8 butterfly)
#pragma unroll
    for (int d = 0; d < 8; ++d) {
        acc8[d] += __shfl_xor(acc8[d], 8, 64);
        acc8[d] += __shfl_xor(acc8[d], 16, 64);
        acc8[d] += __shfl_xor(acc8[d], 32, 64);
    }
    if (lane < 8) {
        union { unsigned short u[8]; uint4 v; } o;
#pragma unroll
        for (int d = 0; d < 8; ++d) o.u[d] = f2bf(acc8[d]);
        *(uint4*)(AO_bf + ((size_t)(b_ * S_LEN + r0 + w)) * DMODEL
                  + h * 64 + lane * 8) = o.v;
    }
}

// ---------------------- out = AO @ Wfc^T + bfc (bf16 A, fp32 W inline-cast)
__global__ __launch_bounds__(256)
void fc_gemm(const unsigned short* __restrict__ AO_bf,
             const float* __restrict__ Wfc,
             const float* __restrict__ bfc, float* __restrict__ out) {
    const int row0 = blockIdx.x * 128;
    const int col0 = blockIdx.y * 128;

    __shared__ unsigned short As[128 * 40];
    __shared__ unsigned short Bs[128 * 40];

    const int t = threadIdx.x;
    const int wid = t >> 6, lane = t & 63;
    const int wm = wid >> 1, wn = wid & 1;
    const int l = lane & 15, quad = lane >> 4;

    f32x4 acc[4][4];
#pragma unroll
    for (int i = 0; i < 4; ++i)
#pragma unroll
        for (int j = 0; j < 4; ++j) {
            float b_ = bfc[col0 + wn * 64 + j * 16 + l];
            acc[i][j] = (f32x4){ b_, b_, b_, b_ };
        }

    for (int k0 = 0; k0 < DMODEL; k0 += 32) {
        uint4 ar[2], br[2];
#pragma unroll
        for (int i = 0; i < 2; ++i) {
            const int c = t + i * 256, r = c >> 2, q = (c & 3) * 8;
            ar[i] = *(const uint4*)(AO_bf + (size_t)(row0 + r) * DMODEL + k0 + q);
            const float* wp = Wfc + (size_t)(col0 + r) * DMODEL + k0 + q;
            float4 w0 = *(const float4*)wp, w1 = *(const float4*)(wp + 4);
            br[i] = pack8(w0, w1);
        }
        __syncthreads();
#pragma unroll
        for (int i = 0; i < 2; ++i) {
            const int c = t + i * 256, r = c >> 2, q = (c & 3) * 8;
            *(uint4*)&As[r * 40 + q] = ar[i];
            *(uint4*)&Bs[r * 40 + q] = br[i];
        }
        __syncthreads();
        bf16x8 a[4], b[4];
#pragma unroll
        for (int i = 0; i < 4; ++i)
            a[i] = *(const bf16x8*)&As[(wm * 64 + i * 16 + l) * 40 + quad * 8];
#pragma unroll
        for (int j = 0; j < 4; ++j)
            b[j] = *(const bf16x8*)&Bs[(wn * 64 + j * 16 + l) * 40 + quad * 8];
#pragma unroll
        for (int i = 0; i < 4; ++i)
#pragma unroll
            for (int j = 0; j < 4; ++j)
                acc[i][j] = __builtin_amdgcn_mfma_f32_16x16x32_bf16(a[i], b[j], acc[i][j], 0, 0, 0);
    }

#pragma unroll
    for (int i = 0; i < 4; ++i)
#pragma unroll
        for (int r = 0; r < 4; ++r) {
            const int m = row0 + wm * 64 + i * 16 + quad * 4 + r;
#pragma unroll
            for (int j = 0; j < 4; ++j) {
                const int n = col0 + wn * 64 + j * 16 + l;
                out[(size_t)m * DMODEL + n] = acc[i][j][r];
            }
        }
}

// ----------------------------------------------------------------------- launch
extern "C" void kernel_launch(void* const* d_in, const int* in_sizes, int n_in,
                              void* d_out, int out_size, void* d_ws, size_t ws_size,
                              hipStream_t stream) {
    const float* q   = (const float*)d_in[0];
    const float* k   = (const float*)d_in[1];
    const float* v   = (const float*)d_in[2];
    const float* Wq  = (const float*)d_in[3];
    const float* bq  = (const float*)d_in[4];
    const float* Wk  = (const float*)d_in[5];
    const float* bk  = (const float*)d_in[6];
    const float* Wv  = (const float*)d_in[7];
    const float* bv  = (const float*)d_in[8];
    const float* Wfc = (const float*)d_in[9];
    const float* bfc = (const float*)d_in[10];

    float* out  = (float*)d_out;                       // [B,S,D] fp32
    float* attn = out + (size_t)M_ROWS * DMODEL;       // [B,H,S,S] fp32

    // bf16 conversion scratch lives in the attn region (overwritten later by
    // attn_fused, after qkv has consumed it): Xq@0, Xk@8M, Xv@16M, W@24/26/28M.
    char* sc = (char*)attn;
    unsigned short* Xq  = (unsigned short*)sc;
    unsigned short* Xk  = (unsigned short*)(sc + (8u << 20));
    unsigned short* Xv  = (unsigned short*)(sc + (16u << 20));
    unsigned short* Wqb = (unsigned short*)(sc + (24u << 20));
    unsigned short* Wkb = (unsigned short*)(sc + (26u << 20));
    unsigned short* Wvb = (unsigned short*)(sc + (28u << 20));

    // workspace: Q_bf [0,8M), K_bf [8,16M), V_bf [16,24M), AO_bf [24,32M)
    char* ws = (char*)d_ws;
    unsigned short* Q_bf  = (unsigned short*)ws;
    unsigned short* K_bf  = (unsigned short*)(ws + (8u << 20));
    unsigned short* V_bf  = (unsigned short*)(ws + (16u << 20));
    unsigned short* AO_bf = (unsigned short*)(ws + (24u << 20));

    cvt_bf16<<<dim3(512, 6), 256, 0, stream>>>(q, k, v, Wq, Wk, Wv,
                                               Xq, Xk, Xv, Wqb, Wkb, Wvb);
    qkv_gemm<<<dim3(32, 8, 3), 256, 0, stream>>>(Xq, Xk, Xv, Wqb, Wkb, Wvb,
                                                  bq, bk, bv, Q_bf, K_bf, V_bf);
    attn_fused<<<dim3(S_LEN / 8, 32), 512, 0, stream>>>(Q_bf, K_bf, V_bf, attn, AO_bf);
    fc_gemm<<<dim3(32, 8), 256, 0, stream>>>(AO_bf, Wfc, bfc, out);
}

// Round 7
// 890.314 us; speedup vs baseline: 1.1029x; 1.1029x over previous
//
#include <hip/hip_runtime.h>
#include <hip/hip_bf16.h>
#include <cstdint>

// MultiHeadAttention w/ sparsemax: B=2, S=2048, D=1024, H=16, DK=64
#define S_LEN  2048
#define DMODEL 1024
#define NHEAD  16
#define M_ROWS 4096                       // B*S

typedef __attribute__((ext_vector_type(8))) short bf16x8;   // MFMA A/B frag (8 bf16)
typedef __attribute__((ext_vector_type(4))) float f32x4;    // MFMA C/D frag

__device__ __forceinline__ unsigned short f2bf(float f) {
    __hip_bfloat16 h = __float2bfloat16(f);
    return __builtin_bit_cast(unsigned short, h);
}
__device__ __forceinline__ float bf2f(unsigned short u) {
    return __builtin_bit_cast(float, (unsigned)u << 16);
}
__device__ __forceinline__ uint4 pack8(float4 a, float4 b) {
    uint4 u;
    u.x = ((unsigned)f2bf(a.y) << 16) | f2bf(a.x);
    u.y = ((unsigned)f2bf(a.w) << 16) | f2bf(a.z);
    u.z = ((unsigned)f2bf(b.y) << 16) | f2bf(b.x);
    u.w = ((unsigned)f2bf(b.w) << 16) | f2bf(b.z);
    return u;
}

// ---------------------------------------------------------------- wave reduce
__device__ __forceinline__ float wave_sum64(float v) {
    v += __shfl_xor(v, 32, 64); v += __shfl_xor(v, 16, 64);
    v += __shfl_xor(v, 8, 64);  v += __shfl_xor(v, 4, 64);
    v += __shfl_xor(v, 2, 64);  v += __shfl_xor(v, 1, 64);
    return v;
}
__device__ __forceinline__ float wave_max64(float v) {
    v = fmaxf(v, __shfl_xor(v, 32, 64)); v = fmaxf(v, __shfl_xor(v, 16, 64));
    v = fmaxf(v, __shfl_xor(v, 8, 64));  v = fmaxf(v, __shfl_xor(v, 4, 64));
    v = fmaxf(v, __shfl_xor(v, 2, 64));  v = fmaxf(v, __shfl_xor(v, 1, 64));
    return v;
}
__device__ __forceinline__ int lanes_below(unsigned long long m) {
    return __builtin_amdgcn_mbcnt_hi((unsigned)(m >> 32),
           __builtin_amdgcn_mbcnt_lo((unsigned)m, 0));
}

// ------------------------------------- qkv: C = A@W^T + b (fp32 in, bf16 MFMA)
// A[4096,1024] fp32, W[1024,1024] fp32 (NT); inline fp32->bf16 in staging.
// (fp32 A/W re-reads are L3-resident: A=16MB, W=4MB << 256MB L3 — round-6's
// pre-conversion to bf16 was a net regression, reverted.)
// Output row-major bf16 [B,S,DMODEL] via LDS-transpose epilogue (16B stores).
// Q output (which==0) is pre-scaled by 0.125 (= 1/sqrt(DK)).
__global__ __launch_bounds__(256)
void qkv_gemm(const float* __restrict__ xq, const float* __restrict__ xk,
              const float* __restrict__ xv,
              const float* __restrict__ Wq, const float* __restrict__ Wk,
              const float* __restrict__ Wv,
              const float* __restrict__ bq, const float* __restrict__ bk,
              const float* __restrict__ bv,
              unsigned short* __restrict__ Q_bf, unsigned short* __restrict__ K_bf,
              unsigned short* __restrict__ V_bf) {
    const int which = blockIdx.z;
    const float* A    = (which == 0) ? xq : (which == 1) ? xk : xv;
    const float* W    = (which == 0) ? Wq : (which == 1) ? Wk : Wv;
    const float* bias = (which == 0) ? bq : (which == 1) ? bk : bv;
    unsigned short* dst = (which == 0) ? Q_bf : (which == 1) ? K_bf : V_bf;
    const float qscale = (which == 0) ? 0.125f : 1.0f;

    const int row0 = blockIdx.x * 128;
    const int col0 = blockIdx.y * 128;

    __shared__ unsigned short SMEM[10240];    // As(5120) + Bs(5120); epilogue aliases
    unsigned short* As = SMEM;                // stride 40 bf16 (2-way free)
    unsigned short* Bs = SMEM + 5120;

    const int t = threadIdx.x;
    const int wid = t >> 6, lane = t & 63;
    const int wm = wid >> 1, wn = wid & 1;
    const int l = lane & 15, quad = lane >> 4;

    f32x4 acc[4][4];
#pragma unroll
    for (int i = 0; i < 4; ++i)
#pragma unroll
        for (int j = 0; j < 4; ++j) {
            float b_ = bias[col0 + wn * 64 + j * 16 + l];
            acc[i][j] = (f32x4){ b_, b_, b_, b_ };
        }

    for (int k0 = 0; k0 < DMODEL; k0 += 32) {
        uint4 ar[2], br[2];
#pragma unroll
        for (int i = 0; i < 2; ++i) {
            const int c = t + i * 256, r = c >> 2, q = (c & 3) * 8;
            const float* ap = A + (size_t)(row0 + r) * DMODEL + k0 + q;
            const float* wp = W + (size_t)(col0 + r) * DMODEL + k0 + q;
            float4 a0 = *(const float4*)ap, a1 = *(const float4*)(ap + 4);
            float4 w0 = *(const float4*)wp, w1 = *(const float4*)(wp + 4);
            ar[i] = pack8(a0, a1);
            br[i] = pack8(w0, w1);
        }
        __syncthreads();
#pragma unroll
        for (int i = 0; i < 2; ++i) {
            const int c = t + i * 256, r = c >> 2, q = (c & 3) * 8;
            *(uint4*)&As[r * 40 + q] = ar[i];
            *(uint4*)&Bs[r * 40 + q] = br[i];
        }
        __syncthreads();
        bf16x8 a[4], b[4];
#pragma unroll
        for (int i = 0; i < 4; ++i)
            a[i] = *(const bf16x8*)&As[(wm * 64 + i * 16 + l) * 40 + quad * 8];
#pragma unroll
        for (int j = 0; j < 4; ++j)
            b[j] = *(const bf16x8*)&Bs[(wn * 64 + j * 16 + l) * 40 + quad * 8];
#pragma unroll
        for (int i = 0; i < 4; ++i)
#pragma unroll
            for (int j = 0; j < 4; ++j)
                acc[i][j] = __builtin_amdgcn_mfma_f32_16x16x32_bf16(a[i], b[j], acc[i][j], 0, 0, 0);
    }

    // ---- epilogue: acc -> LDS (bf16, stride 72 = 16B-aligned rows) -> uint4 stores
    __syncthreads();
    unsigned short* Cs = SMEM;                // 128*72 = 9216 <= 10240
#pragma unroll 1
    for (int jh = 0; jh < 2; ++jh) {
        if (wn == jh) {
#pragma unroll
            for (int i = 0; i < 4; ++i)
#pragma unroll
                for (int j = 0; j < 4; ++j)
#pragma unroll
                    for (int r = 0; r < 4; ++r)
                        Cs[(wm * 64 + i * 16 + quad * 4 + r) * 72 + j * 16 + l] =
                            f2bf(acc[i][j][r] * qscale);
        }
        __syncthreads();
#pragma unroll
        for (int it = 0; it < 4; ++it) {
            const int idx = t + it * 256;           // 0..1023
            const int row = idx >> 3, c8 = (idx & 7) * 8;
            *(uint4*)(dst + (size_t)(row0 + row) * DMODEL + col0 + jh * 64 + c8) =
                *(const uint4*)&Cs[row * 72 + c8];
        }
        __syncthreads();
    }
}

// ------------------------- fused logits + sparsemax + sparse PV -------------------------
// Block = 8 query rows x 2048 cols of one (b,h); 8 waves (512 thr), wave owns row.
// QK^T in 4 column-quarters through a 16 KB LDS transpose region -> z[32]/lane.
// v7: the v4-v6 candidate pre-compaction is DELETED (sigma_z ~ 0.33 makes the
// m-1 threshold admit ~780 of 2048 elements -> the >256 fallback ran every row,
// doing pre-compaction + full Newton + re-compaction). Now: direct register
// Newton where the support COUNT comes from scalar ballot+popcount (wave-
// uniform SGPR; deletes the per-lane kk accumulate and its 6-step shuffle
// reduce), 10-iter cap with exact-fixpoint exit. The attn store pass and the
// single support compaction are fused into one 32-step loop (stores p
// directly). 4-deep prefetched V gather (support ~17 -> 1 iteration).
__global__ __launch_bounds__(512, 6)
void attn_fused(const unsigned short* __restrict__ Q_bf,
                const unsigned short* __restrict__ K_bf,
                const unsigned short* __restrict__ V_bf,
                float* __restrict__ attn,
                unsigned short* __restrict__ AO_bf) {
    const int t = threadIdx.x;
    const int w = t >> 6, lane = t & 63;
    const int l = lane & 15, quad = lane >> 4;
    const int bh = blockIdx.y, b_ = bh >> 4, h = bh & 15;
    const int r0 = blockIdx.x * 8;

    __shared__ uint2 List[8 * 512];    // 32 KB; first 16 KB aliased as transpose buf
    float* LDSf = (float*)List;

    // ---- Q fragments: A rows l&7 -> C rows 0..7 valid (8..15 duplicates)
    const unsigned short* Qp =
        Q_bf + ((size_t)(b_ * S_LEN + r0 + (l & 7))) * DMODEL + h * 64 + quad * 8;
    const bf16x8 a0 = *(const bf16x8*)Qp;
    const bf16x8 a1 = *(const bf16x8*)(Qp + 32);

    float z[32];
    float m = -__builtin_inff();
    // ---- QK^T in 4 column-quarters; wave w covers cols q*512 + [w*64, w*64+64)
#pragma unroll
    for (int q = 0; q < 4; ++q) {
        const unsigned short* Kb =
            K_bf + ((size_t)(b_ * S_LEN + q * 512 + w * 64 + l)) * DMODEL
            + h * 64 + quad * 8;
        f32x4 acc[4];
#pragma unroll
        for (int ct = 0; ct < 4; ++ct) {
            const unsigned short* Kp = Kb + (size_t)(ct * 16) * DMODEL;
            const bf16x8 b0 = *(const bf16x8*)Kp;
            const bf16x8 b1 = *(const bf16x8*)(Kp + 32);
            f32x4 c = {};
            c = __builtin_amdgcn_mfma_f32_16x16x32_bf16(a0, b0, c, 0, 0, 0);
            c = __builtin_amdgcn_mfma_f32_16x16x32_bf16(a1, b1, c, 0, 0, 0);
            acc[ct] = c;                           // Q pre-scaled by 1/8 in qkv
        }
        // transpose: rows = quad*4+r (quads 0,1 hold real rows 0..7)
        if (quad < 2) {
#pragma unroll
            for (int ct = 0; ct < 4; ++ct)
#pragma unroll
                for (int r = 0; r < 4; ++r)
                    LDSf[(quad * 4 + r) * 512 + w * 64 + ct * 16 + l] = acc[ct][r];
        }
        __syncthreads();
#pragma unroll
        for (int j = 0; j < 8; ++j) {
            z[q * 8 + j] = LDSf[w * 512 + j * 64 + lane];
            m = fmaxf(m, z[q * 8 + j]);            // running row max (z hot)
        }
        __syncthreads();
    }

    // ---- row max
    m = wave_max64(m);

    // ---- Newton waterfilling on registers; kk via scalar ballot popcount
    float tau = m - 1.0f;
#pragma unroll 1
    for (int it = 0; it < 10; ++it) {
        float ss = 0.0f;
        int kk = 0;
#pragma unroll
        for (int j = 0; j < 32; ++j) {
            const bool c = z[j] > tau;
            kk += (int)__popcll(__ballot(c));      // wave-uniform SGPR count
            ss += c ? z[j] : 0.0f;
        }
        ss = wave_sum64(ss);
        const float tn = (ss - 1.0f) / (float)kk;  // uniform across wave
        if (tn == tau) break;                      // support stabilized -> exact
        tau = tn;
    }

    // ---- fused: p = max(z-tau,0) -> attn store + support compaction (p stored)
    uint2* list = List + w * 512;
    float* ap = attn + (size_t)bh * S_LEN * S_LEN + (size_t)(r0 + w) * S_LEN;
    int scnt = 0;
#pragma unroll
    for (int jj = 0; jj < 32; ++jj) {
        const float pv = fmaxf(z[jj] - tau, 0.0f);
        __builtin_nontemporal_store(pv, ap + (jj >> 3) * 512 + (jj & 7) * 64 + lane);
        const unsigned long long mk = __ballot(pv > 0.0f);
        if (pv > 0.0f) {
            const int pos = scnt + lanes_below(mk);
            if (pos < 480)
                list[pos] = (uint2){ (unsigned)((jj >> 3) * 512 + (jj & 7) * 64 + lane),
                                     __builtin_bit_cast(unsigned, pv) };
        }
        scnt += (int)__popcll(mk);
    }
    if (scnt > 480) scnt = 480;                    // exactness cap (never hit here)

    // ---- pad list with 32 zero entries (guard-free 4-deep gather)
    if (lane < 32)
        list[scnt + lane] = (uint2){ 0u, 0u };     // p = 0 -> contributes nothing

    // ---- gather: 32 entries per outer iter (4 x 8-lane subgroups, uint4 each)
    const unsigned short* Vh = V_bf + ((size_t)b_ * S_LEN) * DMODEL + h * 64;
    const int sub = lane >> 3, dbase = (lane & 7) * 8;
    float acc8[8] = {};
    const int gmax4 = (scnt + 31) >> 5;
#pragma unroll 1
    for (int g = 0; g < gmax4; ++g) {
        const int b0 = g * 32 + sub;
        const uint2 e0 = list[b0];
        const uint2 e1 = list[b0 + 8];
        const uint2 e2 = list[b0 + 16];
        const uint2 e3 = list[b0 + 24];
        const uint4 v0 = *(const uint4*)(Vh + (size_t)e0.x * DMODEL + dbase);
        const uint4 v1 = *(const uint4*)(Vh + (size_t)e1.x * DMODEL + dbase);
        const uint4 v2 = *(const uint4*)(Vh + (size_t)e2.x * DMODEL + dbase);
        const uint4 v3 = *(const uint4*)(Vh + (size_t)e3.x * DMODEL + dbase);
        const float p0 = __builtin_bit_cast(float, e0.y);
        const float p1 = __builtin_bit_cast(float, e1.y);
        const float p2 = __builtin_bit_cast(float, e2.y);
        const float p3 = __builtin_bit_cast(float, e3.y);
        acc8[0] += p0 * bf2f((unsigned short)(v0.x & 0xffff));
        acc8[1] += p0 * bf2f((unsigned short)(v0.x >> 16));
        acc8[2] += p0 * bf2f((unsigned short)(v0.y & 0xffff));
        acc8[3] += p0 * bf2f((unsigned short)(v0.y >> 16));
        acc8[4] += p0 * bf2f((unsigned short)(v0.z & 0xffff));
        acc8[5] += p0 * bf2f((unsigned short)(v0.z >> 16));
        acc8[6] += p0 * bf2f((unsigned short)(v0.w & 0xffff));
        acc8[7] += p0 * bf2f((unsigned short)(v0.w >> 16));
        acc8[0] += p1 * bf2f((unsigned short)(v1.x & 0xffff));
        acc8[1] += p1 * bf2f((unsigned short)(v1.x >> 16));
        acc8[2] += p1 * bf2f((unsigned short)(v1.y & 0xffff));
        acc8[3] += p1 * bf2f((unsigned short)(v1.y >> 16));
        acc8[4] += p1 * bf2f((unsigned short)(v1.z & 0xffff));
        acc8[5] += p1 * bf2f((unsigned short)(v1.z >> 16));
        acc8[6] += p1 * bf2f((unsigned short)(v1.w & 0xffff));
        acc8[7] += p1 * bf2f((unsigned short)(v1.w >> 16));
        acc8[0] += p2 * bf2f((unsigned short)(v2.x & 0xffff));
        acc8[1] += p2 * bf2f((unsigned short)(v2.x >> 16));
        acc8[2] += p2 * bf2f((unsigned short)(v2.y & 0xffff));
        acc8[3] += p2 * bf2f((unsigned short)(v2.y >> 16));
        acc8[4] += p2 * bf2f((unsigned short)(v2.z & 0xffff));
        acc8[5] += p2 * bf2f((unsigned short)(v2.z >> 16));
        acc8[6] += p2 * bf2f((unsigned short)(v2.w & 0xffff));
        acc8[7] += p2 * bf2f((unsigned short)(v2.w >> 16));
        acc8[0] += p3 * bf2f((unsigned short)(v3.x & 0xffff));
        acc8[1] += p3 * bf2f((unsigned short)(v3.x >> 16));
        acc8[2] += p3 * bf2f((unsigned short)(v3.y & 0xffff));
        acc8[3] += p3 * bf2f((unsigned short)(v3.y >> 16));
        acc8[4] += p3 * bf2f((unsigned short)(v3.z & 0xffff));
        acc8[5] += p3 * bf2f((unsigned short)(v3.z >> 16));
        acc8[6] += p3 * bf2f((unsigned short)(v3.w & 0xffff));
        acc8[7] += p3 * bf2f((unsigned short)(v3.w >> 16));
    }
    // reduce across the 8 subgroups (stride-8 butterfly)
#pragma unroll
    for (int d = 0; d < 8; ++d) {
        acc8[d] += __shfl_xor(acc8[d], 8, 64);
        acc8[d] += __shfl_xor(acc8[d], 16, 64);
        acc8[d] += __shfl_xor(acc8[d], 32, 64);
    }
    if (lane < 8) {
        union { unsigned short u[8]; uint4 v; } o;
#pragma unroll
        for (int d = 0; d < 8; ++d) o.u[d] = f2bf(acc8[d]);
        *(uint4*)(AO_bf + ((size_t)(b_ * S_LEN + r0 + w)) * DMODEL
                  + h * 64 + lane * 8) = o.v;
    }
}

// ---------------------- out = AO @ Wfc^T + bfc (bf16 A, fp32 W inline-cast)
__global__ __launch_bounds__(256)
void fc_gemm(const unsigned short* __restrict__ AO_bf,
             const float* __restrict__ Wfc,
             const float* __restrict__ bfc, float* __restrict__ out) {
    const int row0 = blockIdx.x * 128;
    const int col0 = blockIdx.y * 128;

    __shared__ unsigned short As[128 * 40];
    __shared__ unsigned short Bs[128 * 40];

    const int t = threadIdx.x;
    const int wid = t >> 6, lane = t & 63;
    const int wm = wid >> 1, wn = wid & 1;
    const int l = lane & 15, quad = lane >> 4;

    f32x4 acc[4][4];
#pragma unroll
    for (int i = 0; i < 4; ++i)
#pragma unroll
        for (int j = 0; j < 4; ++j) {
            float b_ = bfc[col0 + wn * 64 + j * 16 + l];
            acc[i][j] = (f32x4){ b_, b_, b_, b_ };
        }

    for (int k0 = 0; k0 < DMODEL; k0 += 32) {
        uint4 ar[2], br[2];
#pragma unroll
        for (int i = 0; i < 2; ++i) {
            const int c = t + i * 256, r = c >> 2, q = (c & 3) * 8;
            ar[i] = *(const uint4*)(AO_bf + (size_t)(row0 + r) * DMODEL + k0 + q);
            const float* wp = Wfc + (size_t)(col0 + r) * DMODEL + k0 + q;
            float4 w0 = *(const float4*)wp, w1 = *(const float4*)(wp + 4);
            br[i] = pack8(w0, w1);
        }
        __syncthreads();
#pragma unroll
        for (int i = 0; i < 2; ++i) {
            const int c = t + i * 256, r = c >> 2, q = (c & 3) * 8;
            *(uint4*)&As[r * 40 + q] = ar[i];
            *(uint4*)&Bs[r * 40 + q] = br[i];
        }
        __syncthreads();
        bf16x8 a[4], b[4];
#pragma unroll
        for (int i = 0; i < 4; ++i)
            a[i] = *(const bf16x8*)&As[(wm * 64 + i * 16 + l) * 40 + quad * 8];
#pragma unroll
        for (int j = 0; j < 4; ++j)
            b[j] = *(const bf16x8*)&Bs[(wn * 64 + j * 16 + l) * 40 + quad * 8];
#pragma unroll
        for (int i = 0; i < 4; ++i)
#pragma unroll
            for (int j = 0; j < 4; ++j)
                acc[i][j] = __builtin_amdgcn_mfma_f32_16x16x32_bf16(a[i], b[j], acc[i][j], 0, 0, 0);
    }

#pragma unroll
    for (int i = 0; i < 4; ++i)
#pragma unroll
        for (int r = 0; r < 4; ++r) {
            const int m = row0 + wm * 64 + i * 16 + quad * 4 + r;
#pragma unroll
            for (int j = 0; j < 4; ++j) {
                const int n = col0 + wn * 64 + j * 16 + l;
                out[(size_t)m * DMODEL + n] = acc[i][j][r];
            }
        }
}

// ----------------------------------------------------------------------- launch
extern "C" void kernel_launch(void* const* d_in, const int* in_sizes, int n_in,
                              void* d_out, int out_size, void* d_ws, size_t ws_size,
                              hipStream_t stream) {
    const float* q   = (const float*)d_in[0];
    const float* k   = (const float*)d_in[1];
    const float* v   = (const float*)d_in[2];
    const float* Wq  = (const float*)d_in[3];
    const float* bq  = (const float*)d_in[4];
    const float* Wk  = (const float*)d_in[5];
    const float* bk  = (const float*)d_in[6];
    const float* Wv  = (const float*)d_in[7];
    const float* bv  = (const float*)d_in[8];
    const float* Wfc = (const float*)d_in[9];
    const float* bfc = (const float*)d_in[10];

    float* out  = (float*)d_out;                       // [B,S,D] fp32
    float* attn = out + (size_t)M_ROWS * DMODEL;       // [B,H,S,S] fp32

    // workspace: Q_bf [0,8M), K_bf [8,16M), V_bf [16,24M), AO_bf [24,32M)
    char* ws = (char*)d_ws;
    unsigned short* Q_bf  = (unsigned short*)ws;
    unsigned short* K_bf  = (unsigned short*)(ws + (8u << 20));
    unsigned short* V_bf  = (unsigned short*)(ws + (16u << 20));
    unsigned short* AO_bf = (unsigned short*)(ws + (24u << 20));

    qkv_gemm<<<dim3(32, 8, 3), 256, 0, stream>>>(q, k, v, Wq, Wk, Wv,
                                                  bq, bk, bv, Q_bf, K_bf, V_bf);
    attn_fused<<<dim3(S_LEN / 8, 32), 512, 0, stream>>>(Q_bf, K_bf, V_bf, attn, AO_bf);
    fc_gemm<<<dim3(32, 8), 256, 0, stream>>>(AO_bf, Wfc, bfc, out);
}

// Round 8
// 794.785 us; speedup vs baseline: 1.2355x; 1.1202x over previous
//
#include <hip/hip_runtime.h>
#include <hip/hip_bf16.h>
#include <cstdint>

// MultiHeadAttention w/ sparsemax: B=2, S=2048, D=1024, H=16, DK=64
#define S_LEN  2048
#define DMODEL 1024
#define NHEAD  16
#define M_ROWS 4096                       // B*S

typedef __attribute__((ext_vector_type(8))) short bf16x8;   // MFMA A/B frag (8 bf16)
typedef __attribute__((ext_vector_type(4))) float f32x4;    // MFMA C/D frag

__device__ __forceinline__ unsigned short f2bf(float f) {
    __hip_bfloat16 h = __float2bfloat16(f);
    return __builtin_bit_cast(unsigned short, h);
}
__device__ __forceinline__ float bf2f(unsigned short u) {
    return __builtin_bit_cast(float, (unsigned)u << 16);
}
__device__ __forceinline__ uint4 pack8(float4 a, float4 b) {
    uint4 u;
    u.x = ((unsigned)f2bf(a.y) << 16) | f2bf(a.x);
    u.y = ((unsigned)f2bf(a.w) << 16) | f2bf(a.z);
    u.z = ((unsigned)f2bf(b.y) << 16) | f2bf(b.x);
    u.w = ((unsigned)f2bf(b.w) << 16) | f2bf(b.z);
    return u;
}

// ---------------------------------------------------------------- wave reduce
__device__ __forceinline__ float wave_sum64(float v) {
    v += __shfl_xor(v, 32, 64); v += __shfl_xor(v, 16, 64);
    v += __shfl_xor(v, 8, 64);  v += __shfl_xor(v, 4, 64);
    v += __shfl_xor(v, 2, 64);  v += __shfl_xor(v, 1, 64);
    return v;
}
__device__ __forceinline__ float wave_max64(float v) {
    v = fmaxf(v, __shfl_xor(v, 32, 64)); v = fmaxf(v, __shfl_xor(v, 16, 64));
    v = fmaxf(v, __shfl_xor(v, 8, 64));  v = fmaxf(v, __shfl_xor(v, 4, 64));
    v = fmaxf(v, __shfl_xor(v, 2, 64));  v = fmaxf(v, __shfl_xor(v, 1, 64));
    return v;
}
__device__ __forceinline__ int lanes_below(unsigned long long m) {
    return __builtin_amdgcn_mbcnt_hi((unsigned)(m >> 32),
           __builtin_amdgcn_mbcnt_lo((unsigned)m, 0));
}

// ------------------------------------- qkv: C = A@W^T + b (fp32 in, bf16 MFMA)
// v8: single-barrier double-buffered LDS — write(buf)->sync->issue next loads->
// MFMA(buf). Loads overlap MFMA+write of the current step instead of draining
// at their own iteration's barrier (the old structure exposed full L2/L3
// latency every K-step: load -> sync[vmcnt(0)] -> ...).
// Q output (which==0) pre-scaled by 0.125 (= 1/sqrt(DK)).
__global__ __launch_bounds__(256)
void qkv_gemm(const float* __restrict__ xq, const float* __restrict__ xk,
              const float* __restrict__ xv,
              const float* __restrict__ Wq, const float* __restrict__ Wk,
              const float* __restrict__ Wv,
              const float* __restrict__ bq, const float* __restrict__ bk,
              const float* __restrict__ bv,
              unsigned short* __restrict__ Q_bf, unsigned short* __restrict__ K_bf,
              unsigned short* __restrict__ V_bf) {
    const int which = blockIdx.z;
    const float* A    = (which == 0) ? xq : (which == 1) ? xk : xv;
    const float* W    = (which == 0) ? Wq : (which == 1) ? Wk : Wv;
    const float* bias = (which == 0) ? bq : (which == 1) ? bk : bv;
    unsigned short* dst = (which == 0) ? Q_bf : (which == 1) ? K_bf : V_bf;
    const float qscale = (which == 0) ? 0.125f : 1.0f;

    const int row0 = blockIdx.x * 128;
    const int col0 = blockIdx.y * 128;

    __shared__ unsigned short SMEM[20480];    // 2 x (As 5120 + Bs 5120); 40 KB
    const int t = threadIdx.x;
    const int wid = t >> 6, lane = t & 63;
    const int wm = wid >> 1, wn = wid & 1;
    const int l = lane & 15, quad = lane >> 4;

    f32x4 acc[4][4];
#pragma unroll
    for (int i = 0; i < 4; ++i)
#pragma unroll
        for (int j = 0; j < 4; ++j) {
            float b_ = bias[col0 + wn * 64 + j * 16 + l];
            acc[i][j] = (f32x4){ b_, b_, b_, b_ };
        }

    uint4 ar[2], br[2];
    // prologue: load K-step 0
#pragma unroll
    for (int i = 0; i < 2; ++i) {
        const int c = t + i * 256, r = c >> 2, q = (c & 3) * 8;
        const float* ap = A + (size_t)(row0 + r) * DMODEL + q;
        const float* wp = W + (size_t)(col0 + r) * DMODEL + q;
        float4 a0 = *(const float4*)ap, a1 = *(const float4*)(ap + 4);
        float4 w0 = *(const float4*)wp, w1 = *(const float4*)(wp + 4);
        ar[i] = pack8(a0, a1);
        br[i] = pack8(w0, w1);
    }

    for (int k0 = 0; k0 < DMODEL; k0 += 32) {
        unsigned short* As = SMEM + ((k0 >> 5) & 1) * 10240;
        unsigned short* Bs = As + 5120;
#pragma unroll
        for (int i = 0; i < 2; ++i) {
            const int c = t + i * 256, r = c >> 2, q = (c & 3) * 8;
            *(uint4*)&As[r * 40 + q] = ar[i];
            *(uint4*)&Bs[r * 40 + q] = br[i];
        }
        __syncthreads();
        if (k0 + 32 < DMODEL) {                // issue next-step loads (overlap)
#pragma unroll
            for (int i = 0; i < 2; ++i) {
                const int c = t + i * 256, r = c >> 2, q = (c & 3) * 8;
                const float* ap = A + (size_t)(row0 + r) * DMODEL + k0 + 32 + q;
                const float* wp = W + (size_t)(col0 + r) * DMODEL + k0 + 32 + q;
                float4 a0 = *(const float4*)ap, a1 = *(const float4*)(ap + 4);
                float4 w0 = *(const float4*)wp, w1 = *(const float4*)(wp + 4);
                ar[i] = pack8(a0, a1);
                br[i] = pack8(w0, w1);
            }
        }
        bf16x8 a[4], b[4];
#pragma unroll
        for (int i = 0; i < 4; ++i)
            a[i] = *(const bf16x8*)&As[(wm * 64 + i * 16 + l) * 40 + quad * 8];
#pragma unroll
        for (int j = 0; j < 4; ++j)
            b[j] = *(const bf16x8*)&Bs[(wn * 64 + j * 16 + l) * 40 + quad * 8];
#pragma unroll
        for (int i = 0; i < 4; ++i)
#pragma unroll
            for (int j = 0; j < 4; ++j)
                acc[i][j] = __builtin_amdgcn_mfma_f32_16x16x32_bf16(a[i], b[j], acc[i][j], 0, 0, 0);
        // no 2nd barrier: next write targets the other buffer; reads of this
        // buffer complete before anyone passes the NEXT sync (barrier proof).
    }

    // ---- epilogue: acc -> LDS (bf16, stride 72) -> uint4 stores
    __syncthreads();
    unsigned short* Cs = SMEM;                // 128*72 = 9216 <= 20480
#pragma unroll 1
    for (int jh = 0; jh < 2; ++jh) {
        if (wn == jh) {
#pragma unroll
            for (int i = 0; i < 4; ++i)
#pragma unroll
                for (int j = 0; j < 4; ++j)
#pragma unroll
                    for (int r = 0; r < 4; ++r)
                        Cs[(wm * 64 + i * 16 + quad * 4 + r) * 72 + j * 16 + l] =
                            f2bf(acc[i][j][r] * qscale);
        }
        __syncthreads();
#pragma unroll
        for (int it = 0; it < 4; ++it) {
            const int idx = t + it * 256;           // 0..1023
            const int row = idx >> 3, c8 = (idx & 7) * 8;
            *(uint4*)(dst + (size_t)(row0 + row) * DMODEL + col0 + jh * 64 + c8) =
                *(const uint4*)&Cs[row * 72 + c8];
        }
        __syncthreads();
    }
}

// ------------------------- fused logits + sparsemax + sparse PV -------------------------
// v8 structure: block = 16 REAL query rows (no duplicate-row MFMA waste),
// 16 waves (1024 thr), wave owns row w. QK^T in 4 column-quarters with
// K-fragment prefetch one quarter ahead and PING-PONG transpose buffers
// (one barrier per quarter, 5 barriers total vs v7's 8 per 8 rows).
// Newton: 1 full-scan iteration from tau0=m-1 gives tau1 (lower bound);
// candidates z>tau1 (~140 < 256) then iterate on 4 registers; support
// compaction from those registers. Full-scan fallback preserves exactness.
__global__ __launch_bounds__(1024, 4)
void attn_fused(const unsigned short* __restrict__ Q_bf,
                const unsigned short* __restrict__ K_bf,
                const unsigned short* __restrict__ V_bf,
                float* __restrict__ attn,
                unsigned short* __restrict__ AO_bf) {
    const int t = threadIdx.x;
    const int w = t >> 6, lane = t & 63;
    const int l = lane & 15, quad = lane >> 4;
    const int bh = blockIdx.y, b_ = bh >> 4, h = bh & 15;
    const int r0 = blockIdx.x * 16;

    __shared__ float TR[2][16][516];   // 66048 B ping-pong transpose (516: 2-way banks)
    uint2* List = (uint2*)&TR[0][0][0]; // aliased after transpose phase (64 KB used)

    // ---- Q fragments: 16 real rows r0+l
    const unsigned short* Qp =
        Q_bf + ((size_t)(b_ * S_LEN + r0 + l)) * DMODEL + h * 64 + quad * 8;
    const bf16x8 a0 = *(const bf16x8*)Qp;
    const bf16x8 a1 = *(const bf16x8*)(Qp + 32);

    // ---- K base: quarter q, tile ct -> row q*512 + w*32 + ct*16 + l
    const unsigned short* KB =
        K_bf + ((size_t)(b_ * S_LEN + w * 32 + l)) * DMODEL + h * 64 + quad * 8;

    float z[32];
    float m = -__builtin_inff();
    bf16x8 cb0[2], cb1[2], nb0[2], nb1[2];
#pragma unroll
    for (int ct = 0; ct < 2; ++ct) {           // prologue: quarter 0 frags
        const unsigned short* Kp = KB + (size_t)(ct * 16) * DMODEL;
        cb0[ct] = *(const bf16x8*)Kp;
        cb1[ct] = *(const bf16x8*)(Kp + 32);
    }
#pragma unroll
    for (int q = 0; q < 4; ++q) {
        if (q < 3) {                            // prefetch quarter q+1 (overlaps MFMA)
#pragma unroll
            for (int ct = 0; ct < 2; ++ct) {
                const unsigned short* Kp =
                    KB + (size_t)((q + 1) * 512 + ct * 16) * DMODEL;
                nb0[ct] = *(const bf16x8*)Kp;
                nb1[ct] = *(const bf16x8*)(Kp + 32);
            }
        }
#pragma unroll
        for (int ct = 0; ct < 2; ++ct) {
            f32x4 c = {};
            c = __builtin_amdgcn_mfma_f32_16x16x32_bf16(a0, cb0[ct], c, 0, 0, 0);
            c = __builtin_amdgcn_mfma_f32_16x16x32_bf16(a1, cb1[ct], c, 0, 0, 0);
#pragma unroll
            for (int r = 0; r < 4; ++r)        // Q pre-scaled by 1/8 in qkv
                TR[q & 1][quad * 4 + r][w * 32 + ct * 16 + l] = c[r];
        }
        __syncthreads();                        // ONE barrier per quarter
#pragma unroll
        for (int j = 0; j < 8; ++j) {
            z[q * 8 + j] = TR[q & 1][w][j * 64 + lane];
            m = fmaxf(m, z[q * 8 + j]);
        }
        if (q < 3) {
#pragma unroll
            for (int ct = 0; ct < 2; ++ct) { cb0[ct] = nb0[ct]; cb1[ct] = nb1[ct]; }
        }
        // next write targets TR[(q+1)&1]; writes to TR[q&1] recur only after
        // the NEXT barrier, by which time all reads of quarter q are done.
    }
    __syncthreads();                            // transpose done -> List may alias

    // ---- row max; Newton iter 1 (full scan) -> tau1 (valid lower bound)
    m = wave_max64(m);
    float tau = m - 1.0f;
    {
        float ss = 0.0f; int kk = 0;
#pragma unroll
        for (int j = 0; j < 32; ++j) {
            const bool c = z[j] > tau;
            kk += (int)__popcll(__ballot(c));
            ss += c ? z[j] : 0.0f;
        }
        ss = wave_sum64(ss);
        tau = (ss - 1.0f) / (float)kk;          // tau1 <= tau*
    }

    // ---- candidate compaction: (col, z) with z > tau1
    uint2* list = List + w * 512;
    int cnt = 0;
#pragma unroll
    for (int jj = 0; jj < 32; ++jj) {
        const float zv = z[jj];
        const unsigned long long mk = __ballot(zv > tau);
        if (zv > tau) {
            const int pos = cnt + lanes_below(mk);
            if (pos < 512)
                list[pos] = (uint2){ (unsigned)((jj >> 3) * 512 + (jj & 7) * 64 + lane),
                                     __builtin_bit_cast(unsigned, zv) };
        }
        cnt += (int)__popcll(mk);
    }

    int scnt = 0;
    if (cnt <= 256) {
        const float NEG = -__builtin_inff();
        const uint2 E0 = list[lane];
        const uint2 E1 = list[64 + lane];
        const uint2 E2 = list[128 + lane];
        const uint2 E3 = list[192 + lane];
        const float zc0 = (lane < cnt)       ? __builtin_bit_cast(float, E0.y) : NEG;
        const float zc1 = (64 + lane < cnt)  ? __builtin_bit_cast(float, E1.y) : NEG;
        const float zc2 = (128 + lane < cnt) ? __builtin_bit_cast(float, E2.y) : NEG;
        const float zc3 = (192 + lane < cnt) ? __builtin_bit_cast(float, E3.y) : NEG;
#pragma unroll 1
        for (int it = 0; it < 12; ++it) {
            float ss = 0.0f; int kk = 0;
            kk += (int)__popcll(__ballot(zc0 > tau)); ss += (zc0 > tau) ? zc0 : 0.0f;
            kk += (int)__popcll(__ballot(zc1 > tau)); ss += (zc1 > tau) ? zc1 : 0.0f;
            kk += (int)__popcll(__ballot(zc2 > tau)); ss += (zc2 > tau) ? zc2 : 0.0f;
            kk += (int)__popcll(__ballot(zc3 > tau)); ss += (zc3 > tau) ? zc3 : 0.0f;
            ss = wave_sum64(ss);
            const float tn = (ss - 1.0f) / (float)kk;
            if (tn == tau) break;               // support stabilized -> exact
            tau = tn;
        }
        // support re-compaction from registers: store (col, p = z - tau)
        unsigned long long mk;
        mk = __ballot(zc0 > tau);
        if (zc0 > tau) list[scnt + lanes_below(mk)] =
            (uint2){ E0.x, __builtin_bit_cast(unsigned, zc0 - tau) };
        scnt += (int)__popcll(mk);
        mk = __ballot(zc1 > tau);
        if (zc1 > tau) list[scnt + lanes_below(mk)] =
            (uint2){ E1.x, __builtin_bit_cast(unsigned, zc1 - tau) };
        scnt += (int)__popcll(mk);
        mk = __ballot(zc2 > tau);
        if (zc2 > tau) list[scnt + lanes_below(mk)] =
            (uint2){ E2.x, __builtin_bit_cast(unsigned, zc2 - tau) };
        scnt += (int)__popcll(mk);
        mk = __ballot(zc3 > tau);
        if (zc3 > tau) list[scnt + lanes_below(mk)] =
            (uint2){ E3.x, __builtin_bit_cast(unsigned, zc3 - tau) };
        scnt += (int)__popcll(mk);
    } else {
        // fallback: continue full-scan Newton from tau1 (exactness preserved)
#pragma unroll 1
        for (int it = 0; it < 9; ++it) {
            float ss = 0.0f; int kk = 0;
#pragma unroll
            for (int j = 0; j < 32; ++j) {
                const bool c = z[j] > tau;
                kk += (int)__popcll(__ballot(c));
                ss += c ? z[j] : 0.0f;
            }
            ss = wave_sum64(ss);
            const float tn = (ss - 1.0f) / (float)kk;
            if (tn == tau) break;
            tau = tn;
        }
        // compact support from z, storing p
#pragma unroll
        for (int jj = 0; jj < 32; ++jj) {
            const float zv = z[jj];
            const unsigned long long mk = __ballot(zv > tau);
            if (zv > tau) {
                const int pos = scnt + lanes_below(mk);
                if (pos < 480)
                    list[pos] = (uint2){ (unsigned)((jj >> 3) * 512 + (jj & 7) * 64 + lane),
                                         __builtin_bit_cast(unsigned, zv - tau) };
            }
            scnt += (int)__popcll(mk);
        }
        if (scnt > 480) scnt = 480;
    }

    // ---- p = max(z - tau, 0); coalesced nontemporal fp32 attn row store
    float* ap = attn + (size_t)bh * S_LEN * S_LEN + (size_t)(r0 + w) * S_LEN;
#pragma unroll
    for (int jj = 0; jj < 32; ++jj) {
        const float pv = fmaxf(z[jj] - tau, 0.0f);
        __builtin_nontemporal_store(pv, ap + (jj >> 3) * 512 + (jj & 7) * 64 + lane);
    }

    // ---- pad list with 32 zero entries (guard-free 4-deep gather)
    if (lane < 32)
        list[scnt + lane] = (uint2){ 0u, 0u };  // p = 0 -> contributes nothing

    // ---- gather: 32 entries per outer iter (4 x 8-lane subgroups, uint4 each)
    const unsigned short* Vh = V_bf + ((size_t)b_ * S_LEN) * DMODEL + h * 64;
    const int sub = lane >> 3, dbase = (lane & 7) * 8;
    float acc8[8] = {};
    const int gmax4 = (scnt + 31) >> 5;
#pragma unroll 1
    for (int g = 0; g < gmax4; ++g) {
        const int b0 = g * 32 + sub;
        const uint2 e0 = list[b0];
        const uint2 e1 = list[b0 + 8];
        const uint2 e2 = list[b0 + 16];
        const uint2 e3 = list[b0 + 24];
        const uint4 v0 = *(const uint4*)(Vh + (size_t)e0.x * DMODEL + dbase);
        const uint4 v1 = *(const uint4*)(Vh + (size_t)e1.x * DMODEL + dbase);
        const uint4 v2 = *(const uint4*)(Vh + (size_t)e2.x * DMODEL + dbase);
        const uint4 v3 = *(const uint4*)(Vh + (size_t)e3.x * DMODEL + dbase);
        const float p0 = __builtin_bit_cast(float, e0.y);
        const float p1 = __builtin_bit_cast(float, e1.y);
        const float p2 = __builtin_bit_cast(float, e2.y);
        const float p3 = __builtin_bit_cast(float, e3.y);
        acc8[0] += p0 * bf2f((unsigned short)(v0.x & 0xffff));
        acc8[1] += p0 * bf2f((unsigned short)(v0.x >> 16));
        acc8[2] += p0 * bf2f((unsigned short)(v0.y & 0xffff));
        acc8[3] += p0 * bf2f((unsigned short)(v0.y >> 16));
        acc8[4] += p0 * bf2f((unsigned short)(v0.z & 0xffff));
        acc8[5] += p0 * bf2f((unsigned short)(v0.z >> 16));
        acc8[6] += p0 * bf2f((unsigned short)(v0.w & 0xffff));
        acc8[7] += p0 * bf2f((unsigned short)(v0.w >> 16));
        acc8[0] += p1 * bf2f((unsigned short)(v1.x & 0xffff));
        acc8[1] += p1 * bf2f((unsigned short)(v1.x >> 16));
        acc8[2] += p1 * bf2f((unsigned short)(v1.y & 0xffff));
        acc8[3] += p1 * bf2f((unsigned short)(v1.y >> 16));
        acc8[4] += p1 * bf2f((unsigned short)(v1.z & 0xffff));
        acc8[5] += p1 * bf2f((unsigned short)(v1.z >> 16));
        acc8[6] += p1 * bf2f((unsigned short)(v1.w & 0xffff));
        acc8[7] += p1 * bf2f((unsigned short)(v1.w >> 16));
        acc8[0] += p2 * bf2f((unsigned short)(v2.x & 0xffff));
        acc8[1] += p2 * bf2f((unsigned short)(v2.x >> 16));
        acc8[2] += p2 * bf2f((unsigned short)(v2.y & 0xffff));
        acc8[3] += p2 * bf2f((unsigned short)(v2.y >> 16));
        acc8[4] += p2 * bf2f((unsigned short)(v2.z & 0xffff));
        acc8[5] += p2 * bf2f((unsigned short)(v2.z >> 16));
        acc8[6] += p2 * bf2f((unsigned short)(v2.w & 0xffff));
        acc8[7] += p2 * bf2f((unsigned short)(v2.w >> 16));
        acc8[0] += p3 * bf2f((unsigned short)(v3.x & 0xffff));
        acc8[1] += p3 * bf2f((unsigned short)(v3.x >> 16));
        acc8[2] += p3 * bf2f((unsigned short)(v3.y & 0xffff));
        acc8[3] += p3 * bf2f((unsigned short)(v3.y >> 16));
        acc8[4] += p3 * bf2f((unsigned short)(v3.z & 0xffff));
        acc8[5] += p3 * bf2f((unsigned short)(v3.z >> 16));
        acc8[6] += p3 * bf2f((unsigned short)(v3.w & 0xffff));
        acc8[7] += p3 * bf2f((unsigned short)(v3.w >> 16));
    }
    // reduce across the 8 subgroups (stride-8 butterfly)
#pragma unroll
    for (int d = 0; d < 8; ++d) {
        acc8[d] += __shfl_xor(acc8[d], 8, 64);
        acc8[d] += __shfl_xor(acc8[d], 16, 64);
        acc8[d] += __shfl_xor(acc8[d], 32, 64);
    }
    if (lane < 8) {
        union { unsigned short u[8]; uint4 v; } o;
#pragma unroll
        for (int d = 0; d < 8; ++d) o.u[d] = f2bf(acc8[d]);
        *(uint4*)(AO_bf + ((size_t)(b_ * S_LEN + r0 + w)) * DMODEL
                  + h * 64 + lane * 8) = o.v;
    }
}

// ---------------------- out = AO @ Wfc^T + bfc (bf16 A, fp32 W inline-cast)
// v8: same single-barrier double-buffered LDS pipeline as qkv.
__global__ __launch_bounds__(256)
void fc_gemm(const unsigned short* __restrict__ AO_bf,
             const float* __restrict__ Wfc,
             const float* __restrict__ bfc, float* __restrict__ out) {
    const int row0 = blockIdx.x * 128;
    const int col0 = blockIdx.y * 128;

    __shared__ unsigned short SMEM[20480];    // 2 x (As 5120 + Bs 5120); 40 KB

    const int t = threadIdx.x;
    const int wid = t >> 6, lane = t & 63;
    const int wm = wid >> 1, wn = wid & 1;
    const int l = lane & 15, quad = lane >> 4;

    f32x4 acc[4][4];
#pragma unroll
    for (int i = 0; i < 4; ++i)
#pragma unroll
        for (int j = 0; j < 4; ++j) {
            float b_ = bfc[col0 + wn * 64 + j * 16 + l];
            acc[i][j] = (f32x4){ b_, b_, b_, b_ };
        }

    uint4 ar[2], br[2];
#pragma unroll
    for (int i = 0; i < 2; ++i) {
        const int c = t + i * 256, r = c >> 2, q = (c & 3) * 8;
        ar[i] = *(const uint4*)(AO_bf + (size_t)(row0 + r) * DMODEL + q);
        const float* wp = Wfc + (size_t)(col0 + r) * DMODEL + q;
        float4 w0 = *(const float4*)wp, w1 = *(const float4*)(wp + 4);
        br[i] = pack8(w0, w1);
    }

    for (int k0 = 0; k0 < DMODEL; k0 += 32) {
        unsigned short* As = SMEM + ((k0 >> 5) & 1) * 10240;
        unsigned short* Bs = As + 5120;
#pragma unroll
        for (int i = 0; i < 2; ++i) {
            const int c = t + i * 256, r = c >> 2, q = (c & 3) * 8;
            *(uint4*)&As[r * 40 + q] = ar[i];
            *(uint4*)&Bs[r * 40 + q] = br[i];
        }
        __syncthreads();
        if (k0 + 32 < DMODEL) {
#pragma unroll
            for (int i = 0; i < 2; ++i) {
                const int c = t + i * 256, r = c >> 2, q = (c & 3) * 8;
                ar[i] = *(const uint4*)(AO_bf + (size_t)(row0 + r) * DMODEL + k0 + 32 + q);
                const float* wp = Wfc + (size_t)(col0 + r) * DMODEL + k0 + 32 + q;
                float4 w0 = *(const float4*)wp, w1 = *(const float4*)(wp + 4);
                br[i] = pack8(w0, w1);
            }
        }
        bf16x8 a[4], b[4];
#pragma unroll
        for (int i = 0; i < 4; ++i)
            a[i] = *(const bf16x8*)&As[(wm * 64 + i * 16 + l) * 40 + quad * 8];
#pragma unroll
        for (int j = 0; j < 4; ++j)
            b[j] = *(const bf16x8*)&Bs[(wn * 64 + j * 16 + l) * 40 + quad * 8];
#pragma unroll
        for (int i = 0; i < 4; ++i)
#pragma unroll
            for (int j = 0; j < 4; ++j)
                acc[i][j] = __builtin_amdgcn_mfma_f32_16x16x32_bf16(a[i], b[j], acc[i][j], 0, 0, 0);
    }

#pragma unroll
    for (int i = 0; i < 4; ++i)
#pragma unroll
        for (int r = 0; r < 4; ++r) {
            const int m = row0 + wm * 64 + i * 16 + quad * 4 + r;
#pragma unroll
            for (int j = 0; j < 4; ++j) {
                const int n = col0 + wn * 64 + j * 16 + l;
                out[(size_t)m * DMODEL + n] = acc[i][j][r];
            }
        }
}

// ----------------------------------------------------------------------- launch
extern "C" void kernel_launch(void* const* d_in, const int* in_sizes, int n_in,
                              void* d_out, int out_size, void* d_ws, size_t ws_size,
                              hipStream_t stream) {
    const float* q   = (const float*)d_in[0];
    const float* k   = (const float*)d_in[1];
    const float* v   = (const float*)d_in[2];
    const float* Wq  = (const float*)d_in[3];
    const float* bq  = (const float*)d_in[4];
    const float* Wk  = (const float*)d_in[5];
    const float* bk  = (const float*)d_in[6];
    const float* Wv  = (const float*)d_in[7];
    const float* bv  = (const float*)d_in[8];
    const float* Wfc = (const float*)d_in[9];
    const float* bfc = (const float*)d_in[10];

    float* out  = (float*)d_out;                       // [B,S,D] fp32
    float* attn = out + (size_t)M_ROWS * DMODEL;       // [B,H,S,S] fp32

    // workspace: Q_bf [0,8M), K_bf [8,16M), V_bf [16,24M), AO_bf [24,32M)
    char* ws = (char*)d_ws;
    unsigned short* Q_bf  = (unsigned short*)ws;
    unsigned short* K_bf  = (unsigned short*)(ws + (8u << 20));
    unsigned short* V_bf  = (unsigned short*)(ws + (16u << 20));
    unsigned short* AO_bf = (unsigned short*)(ws + (24u << 20));

    qkv_gemm<<<dim3(32, 8, 3), 256, 0, stream>>>(q, k, v, Wq, Wk, Wv,
                                                  bq, bk, bv, Q_bf, K_bf, V_bf);
    attn_fused<<<dim3(S_LEN / 16, 32), 1024, 0, stream>>>(Q_bf, K_bf, V_bf, attn, AO_bf);
    fc_gemm<<<dim3(32, 8), 256, 0, stream>>>(AO_bf, Wfc, bfc, out);
}

// Round 9
// 793.979 us; speedup vs baseline: 1.2368x; 1.0010x over previous
//
#include <hip/hip_runtime.h>
#include <hip/hip_bf16.h>
#include <cstdint>

// MultiHeadAttention w/ sparsemax: B=2, S=2048, D=1024, H=16, DK=64
#define S_LEN  2048
#define DMODEL 1024
#define NHEAD  16
#define M_ROWS 4096                       // B*S

typedef __attribute__((ext_vector_type(8))) short bf16x8;   // MFMA A/B frag (8 bf16)
typedef __attribute__((ext_vector_type(4))) float f32x4;    // MFMA C/D frag

__device__ __forceinline__ unsigned short f2bf(float f) {
    __hip_bfloat16 h = __float2bfloat16(f);
    return __builtin_bit_cast(unsigned short, h);
}
__device__ __forceinline__ float bf2f(unsigned short u) {
    return __builtin_bit_cast(float, (unsigned)u << 16);
}
__device__ __forceinline__ uint4 pack8(float4 a, float4 b) {
    uint4 u;
    u.x = ((unsigned)f2bf(a.y) << 16) | f2bf(a.x);
    u.y = ((unsigned)f2bf(a.w) << 16) | f2bf(a.z);
    u.z = ((unsigned)f2bf(b.y) << 16) | f2bf(b.x);
    u.w = ((unsigned)f2bf(b.w) << 16) | f2bf(b.z);
    return u;
}

// ---------------------------------------------------------------- wave reduce
__device__ __forceinline__ float wave_sum64(float v) {
    v += __shfl_xor(v, 32, 64); v += __shfl_xor(v, 16, 64);
    v += __shfl_xor(v, 8, 64);  v += __shfl_xor(v, 4, 64);
    v += __shfl_xor(v, 2, 64);  v += __shfl_xor(v, 1, 64);
    return v;
}
__device__ __forceinline__ float wave_max64(float v) {
    v = fmaxf(v, __shfl_xor(v, 32, 64)); v = fmaxf(v, __shfl_xor(v, 16, 64));
    v = fmaxf(v, __shfl_xor(v, 8, 64));  v = fmaxf(v, __shfl_xor(v, 4, 64));
    v = fmaxf(v, __shfl_xor(v, 2, 64));  v = fmaxf(v, __shfl_xor(v, 1, 64));
    return v;
}
__device__ __forceinline__ int lanes_below(unsigned long long m) {
    return __builtin_amdgcn_mbcnt_hi((unsigned)(m >> 32),
           __builtin_amdgcn_mbcnt_lo((unsigned)m, 0));
}

// ------------------------------------- qkv: C = A@W^T + b (fp32 in, bf16 MFMA)
// Single-barrier double-buffered LDS: write(buf)->sync->issue next loads->
// MFMA(buf). Loads overlap MFMA+write of the current step.
// Q output (which==0) pre-scaled by 0.125 (= 1/sqrt(DK)).
__global__ __launch_bounds__(256)
void qkv_gemm(const float* __restrict__ xq, const float* __restrict__ xk,
              const float* __restrict__ xv,
              const float* __restrict__ Wq, const float* __restrict__ Wk,
              const float* __restrict__ Wv,
              const float* __restrict__ bq, const float* __restrict__ bk,
              const float* __restrict__ bv,
              unsigned short* __restrict__ Q_bf, unsigned short* __restrict__ K_bf,
              unsigned short* __restrict__ V_bf) {
    const int which = blockIdx.z;
    const float* A    = (which == 0) ? xq : (which == 1) ? xk : xv;
    const float* W    = (which == 0) ? Wq : (which == 1) ? Wk : Wv;
    const float* bias = (which == 0) ? bq : (which == 1) ? bk : bv;
    unsigned short* dst = (which == 0) ? Q_bf : (which == 1) ? K_bf : V_bf;
    const float qscale = (which == 0) ? 0.125f : 1.0f;

    const int row0 = blockIdx.x * 128;
    const int col0 = blockIdx.y * 128;

    __shared__ unsigned short SMEM[20480];    // 2 x (As 5120 + Bs 5120); 40 KB
    const int t = threadIdx.x;
    const int wid = t >> 6, lane = t & 63;
    const int wm = wid >> 1, wn = wid & 1;
    const int l = lane & 15, quad = lane >> 4;

    f32x4 acc[4][4];
#pragma unroll
    for (int i = 0; i < 4; ++i)
#pragma unroll
        for (int j = 0; j < 4; ++j) {
            float b_ = bias[col0 + wn * 64 + j * 16 + l];
            acc[i][j] = (f32x4){ b_, b_, b_, b_ };
        }

    uint4 ar[2], br[2];
    // prologue: load K-step 0
#pragma unroll
    for (int i = 0; i < 2; ++i) {
        const int c = t + i * 256, r = c >> 2, q = (c & 3) * 8;
        const float* ap = A + (size_t)(row0 + r) * DMODEL + q;
        const float* wp = W + (size_t)(col0 + r) * DMODEL + q;
        float4 a0 = *(const float4*)ap, a1 = *(const float4*)(ap + 4);
        float4 w0 = *(const float4*)wp, w1 = *(const float4*)(wp + 4);
        ar[i] = pack8(a0, a1);
        br[i] = pack8(w0, w1);
    }

    for (int k0 = 0; k0 < DMODEL; k0 += 32) {
        unsigned short* As = SMEM + ((k0 >> 5) & 1) * 10240;
        unsigned short* Bs = As + 5120;
#pragma unroll
        for (int i = 0; i < 2; ++i) {
            const int c = t + i * 256, r = c >> 2, q = (c & 3) * 8;
            *(uint4*)&As[r * 40 + q] = ar[i];
            *(uint4*)&Bs[r * 40 + q] = br[i];
        }
        __syncthreads();
        if (k0 + 32 < DMODEL) {                // issue next-step loads (overlap)
#pragma unroll
            for (int i = 0; i < 2; ++i) {
                const int c = t + i * 256, r = c >> 2, q = (c & 3) * 8;
                const float* ap = A + (size_t)(row0 + r) * DMODEL + k0 + 32 + q;
                const float* wp = W + (size_t)(col0 + r) * DMODEL + k0 + 32 + q;
                float4 a0 = *(const float4*)ap, a1 = *(const float4*)(ap + 4);
                float4 w0 = *(const float4*)wp, w1 = *(const float4*)(wp + 4);
                ar[i] = pack8(a0, a1);
                br[i] = pack8(w0, w1);
            }
        }
        bf16x8 a[4], b[4];
#pragma unroll
        for (int i = 0; i < 4; ++i)
            a[i] = *(const bf16x8*)&As[(wm * 64 + i * 16 + l) * 40 + quad * 8];
#pragma unroll
        for (int j = 0; j < 4; ++j)
            b[j] = *(const bf16x8*)&Bs[(wn * 64 + j * 16 + l) * 40 + quad * 8];
#pragma unroll
        for (int i = 0; i < 4; ++i)
#pragma unroll
            for (int j = 0; j < 4; ++j)
                acc[i][j] = __builtin_amdgcn_mfma_f32_16x16x32_bf16(a[i], b[j], acc[i][j], 0, 0, 0);
        // no 2nd barrier: next write targets the other buffer.
    }

    // ---- epilogue: acc -> LDS (bf16, stride 72) -> uint4 stores
    __syncthreads();
    unsigned short* Cs = SMEM;                // 128*72 = 9216 <= 20480
#pragma unroll 1
    for (int jh = 0; jh < 2; ++jh) {
        if (wn == jh) {
#pragma unroll
            for (int i = 0; i < 4; ++i)
#pragma unroll
                for (int j = 0; j < 4; ++j)
#pragma unroll
                    for (int r = 0; r < 4; ++r)
                        Cs[(wm * 64 + i * 16 + quad * 4 + r) * 72 + j * 16 + l] =
                            f2bf(acc[i][j][r] * qscale);
        }
        __syncthreads();
#pragma unroll
        for (int it = 0; it < 4; ++it) {
            const int idx = t + it * 256;           // 0..1023
            const int row = idx >> 3, c8 = (idx & 7) * 8;
            *(uint4*)(dst + (size_t)(row0 + row) * DMODEL + col0 + jh * 64 + c8) =
                *(const uint4*)&Cs[row * 72 + c8];
        }
        __syncthreads();
    }
}

// ------------------------- fused logits + sparsemax + sparse PV -------------------------
// v9 = v8 + gather/store reorder: the first gather block's list entries and
// V loads are issued BEFORE the 32-store attn burst. vmcnt is an in-order
// counter, so in v8 the first PV FMA's waitcnt implied draining all 32 HBM
// stores (~600+ cyc on every row's critical path). With loads older than
// stores, the FMA waits only on the loads; stores drain in the shadow of the
// butterfly + other waves.
__global__ __launch_bounds__(1024, 4)
void attn_fused(const unsigned short* __restrict__ Q_bf,
                const unsigned short* __restrict__ K_bf,
                const unsigned short* __restrict__ V_bf,
                float* __restrict__ attn,
                unsigned short* __restrict__ AO_bf) {
    const int t = threadIdx.x;
    const int w = t >> 6, lane = t & 63;
    const int l = lane & 15, quad = lane >> 4;
    const int bh = blockIdx.y, b_ = bh >> 4, h = bh & 15;
    const int r0 = blockIdx.x * 16;

    __shared__ float TR[2][16][516];   // 66048 B ping-pong transpose (516: 2-way banks)
    uint2* List = (uint2*)&TR[0][0][0]; // aliased after transpose phase (64 KB used)

    // ---- Q fragments: 16 real rows r0+l
    const unsigned short* Qp =
        Q_bf + ((size_t)(b_ * S_LEN + r0 + l)) * DMODEL + h * 64 + quad * 8;
    const bf16x8 a0 = *(const bf16x8*)Qp;
    const bf16x8 a1 = *(const bf16x8*)(Qp + 32);

    // ---- K base: quarter q, tile ct -> row q*512 + w*32 + ct*16 + l
    const unsigned short* KB =
        K_bf + ((size_t)(b_ * S_LEN + w * 32 + l)) * DMODEL + h * 64 + quad * 8;

    float z[32];
    float m = -__builtin_inff();
    bf16x8 cb0[2], cb1[2], nb0[2], nb1[2];
#pragma unroll
    for (int ct = 0; ct < 2; ++ct) {           // prologue: quarter 0 frags
        const unsigned short* Kp = KB + (size_t)(ct * 16) * DMODEL;
        cb0[ct] = *(const bf16x8*)Kp;
        cb1[ct] = *(const bf16x8*)(Kp + 32);
    }
#pragma unroll
    for (int q = 0; q < 4; ++q) {
        if (q < 3) {                            // prefetch quarter q+1 (overlaps MFMA)
#pragma unroll
            for (int ct = 0; ct < 2; ++ct) {
                const unsigned short* Kp =
                    KB + (size_t)((q + 1) * 512 + ct * 16) * DMODEL;
                nb0[ct] = *(const bf16x8*)Kp;
                nb1[ct] = *(const bf16x8*)(Kp + 32);
            }
        }
#pragma unroll
        for (int ct = 0; ct < 2; ++ct) {
            f32x4 c = {};
            c = __builtin_amdgcn_mfma_f32_16x16x32_bf16(a0, cb0[ct], c, 0, 0, 0);
            c = __builtin_amdgcn_mfma_f32_16x16x32_bf16(a1, cb1[ct], c, 0, 0, 0);
#pragma unroll
            for (int r = 0; r < 4; ++r)        // Q pre-scaled by 1/8 in qkv
                TR[q & 1][quad * 4 + r][w * 32 + ct * 16 + l] = c[r];
        }
        __syncthreads();                        // ONE barrier per quarter
#pragma unroll
        for (int j = 0; j < 8; ++j) {
            z[q * 8 + j] = TR[q & 1][w][j * 64 + lane];
            m = fmaxf(m, z[q * 8 + j]);
        }
        if (q < 3) {
#pragma unroll
            for (int ct = 0; ct < 2; ++ct) { cb0[ct] = nb0[ct]; cb1[ct] = nb1[ct]; }
        }
    }
    __syncthreads();                            // transpose done -> List may alias

    // ---- row max; Newton iter 1 (full scan) -> tau1 (valid lower bound)
    m = wave_max64(m);
    float tau = m - 1.0f;
    {
        float ss = 0.0f; int kk = 0;
#pragma unroll
        for (int j = 0; j < 32; ++j) {
            const bool c = z[j] > tau;
            kk += (int)__popcll(__ballot(c));
            ss += c ? z[j] : 0.0f;
        }
        ss = wave_sum64(ss);
        tau = (ss - 1.0f) / (float)kk;          // tau1 <= tau*
    }

    // ---- candidate compaction: (col, z) with z > tau1
    uint2* list = List + w * 512;
    int cnt = 0;
#pragma unroll
    for (int jj = 0; jj < 32; ++jj) {
        const float zv = z[jj];
        const unsigned long long mk = __ballot(zv > tau);
        if (zv > tau) {
            const int pos = cnt + lanes_below(mk);
            if (pos < 512)
                list[pos] = (uint2){ (unsigned)((jj >> 3) * 512 + (jj & 7) * 64 + lane),
                                     __builtin_bit_cast(unsigned, zv) };
        }
        cnt += (int)__popcll(mk);
    }

    int scnt = 0;
    if (cnt <= 256) {
        const float NEG = -__builtin_inff();
        const uint2 E0 = list[lane];
        const uint2 E1 = list[64 + lane];
        const uint2 E2 = list[128 + lane];
        const uint2 E3 = list[192 + lane];
        const float zc0 = (lane < cnt)       ? __builtin_bit_cast(float, E0.y) : NEG;
        const float zc1 = (64 + lane < cnt)  ? __builtin_bit_cast(float, E1.y) : NEG;
        const float zc2 = (128 + lane < cnt) ? __builtin_bit_cast(float, E2.y) : NEG;
        const float zc3 = (192 + lane < cnt) ? __builtin_bit_cast(float, E3.y) : NEG;
#pragma unroll 1
        for (int it = 0; it < 12; ++it) {
            float ss = 0.0f; int kk = 0;
            kk += (int)__popcll(__ballot(zc0 > tau)); ss += (zc0 > tau) ? zc0 : 0.0f;
            kk += (int)__popcll(__ballot(zc1 > tau)); ss += (zc1 > tau) ? zc1 : 0.0f;
            kk += (int)__popcll(__ballot(zc2 > tau)); ss += (zc2 > tau) ? zc2 : 0.0f;
            kk += (int)__popcll(__ballot(zc3 > tau)); ss += (zc3 > tau) ? zc3 : 0.0f;
            ss = wave_sum64(ss);
            const float tn = (ss - 1.0f) / (float)kk;
            if (tn == tau) break;               // support stabilized -> exact
            tau = tn;
        }
        // support re-compaction from registers: store (col, p = z - tau)
        unsigned long long mk;
        mk = __ballot(zc0 > tau);
        if (zc0 > tau) list[scnt + lanes_below(mk)] =
            (uint2){ E0.x, __builtin_bit_cast(unsigned, zc0 - tau) };
        scnt += (int)__popcll(mk);
        mk = __ballot(zc1 > tau);
        if (zc1 > tau) list[scnt + lanes_below(mk)] =
            (uint2){ E1.x, __builtin_bit_cast(unsigned, zc1 - tau) };
        scnt += (int)__popcll(mk);
        mk = __ballot(zc2 > tau);
        if (zc2 > tau) list[scnt + lanes_below(mk)] =
            (uint2){ E2.x, __builtin_bit_cast(unsigned, zc2 - tau) };
        scnt += (int)__popcll(mk);
        mk = __ballot(zc3 > tau);
        if (zc3 > tau) list[scnt + lanes_below(mk)] =
            (uint2){ E3.x, __builtin_bit_cast(unsigned, zc3 - tau) };
        scnt += (int)__popcll(mk);
    } else {
        // fallback: continue full-scan Newton from tau1 (exactness preserved)
#pragma unroll 1
        for (int it = 0; it < 9; ++it) {
            float ss = 0.0f; int kk = 0;
#pragma unroll
            for (int j = 0; j < 32; ++j) {
                const bool c = z[j] > tau;
                kk += (int)__popcll(__ballot(c));
                ss += c ? z[j] : 0.0f;
            }
            ss = wave_sum64(ss);
            const float tn = (ss - 1.0f) / (float)kk;
            if (tn == tau) break;
            tau = tn;
        }
        // compact support from z, storing p
#pragma unroll
        for (int jj = 0; jj < 32; ++jj) {
            const float zv = z[jj];
            const unsigned long long mk = __ballot(zv > tau);
            if (zv > tau) {
                const int pos = scnt + lanes_below(mk);
                if (pos < 480)
                    list[pos] = (uint2){ (unsigned)((jj >> 3) * 512 + (jj & 7) * 64 + lane),
                                         __builtin_bit_cast(unsigned, zv - tau) };
            }
            scnt += (int)__popcll(mk);
        }
        if (scnt > 480) scnt = 480;
    }

    // ---- pad list with 32 zero entries (guard-free gather)
    if (lane < 32)
        list[scnt + lane] = (uint2){ 0u, 0u };  // p = 0 -> contributes nothing

    // ---- PREFETCH gather block 0: list entries + V loads issued BEFORE the
    //      attn store burst (loads older than stores in the vmcnt queue).
    const unsigned short* Vh = V_bf + ((size_t)b_ * S_LEN) * DMODEL + h * 64;
    const int sub = lane >> 3, dbase = (lane & 7) * 8;
    const uint2 e0 = list[sub];
    const uint2 e1 = list[sub + 8];
    const uint2 e2 = list[sub + 16];
    const uint2 e3 = list[sub + 24];
    const uint4 v0 = *(const uint4*)(Vh + (size_t)e0.x * DMODEL + dbase);
    const uint4 v1 = *(const uint4*)(Vh + (size_t)e1.x * DMODEL + dbase);
    const uint4 v2 = *(const uint4*)(Vh + (size_t)e2.x * DMODEL + dbase);
    const uint4 v3 = *(const uint4*)(Vh + (size_t)e3.x * DMODEL + dbase);

    // ---- attn store burst: p = max(z - tau, 0), coalesced nontemporal fp32
    float* ap = attn + (size_t)bh * S_LEN * S_LEN + (size_t)(r0 + w) * S_LEN;
#pragma unroll
    for (int jj = 0; jj < 32; ++jj) {
        const float pv = fmaxf(z[jj] - tau, 0.0f);
        __builtin_nontemporal_store(pv, ap + (jj >> 3) * 512 + (jj & 7) * 64 + lane);
    }

    // ---- FMA block 0 (waits only on the prefetched loads, not the stores)
    float acc8[8] = {};
    {
        const float p0 = __builtin_bit_cast(float, e0.y);
        const float p1 = __builtin_bit_cast(float, e1.y);
        const float p2 = __builtin_bit_cast(float, e2.y);
        const float p3 = __builtin_bit_cast(float, e3.y);
        acc8[0] += p0 * bf2f((unsigned short)(v0.x & 0xffff));
        acc8[1] += p0 * bf2f((unsigned short)(v0.x >> 16));
        acc8[2] += p0 * bf2f((unsigned short)(v0.y & 0xffff));
        acc8[3] += p0 * bf2f((unsigned short)(v0.y >> 16));
        acc8[4] += p0 * bf2f((unsigned short)(v0.z & 0xffff));
        acc8[5] += p0 * bf2f((unsigned short)(v0.z >> 16));
        acc8[6] += p0 * bf2f((unsigned short)(v0.w & 0xffff));
        acc8[7] += p0 * bf2f((unsigned short)(v0.w >> 16));
        acc8[0] += p1 * bf2f((unsigned short)(v1.x & 0xffff));
        acc8[1] += p1 * bf2f((unsigned short)(v1.x >> 16));
        acc8[2] += p1 * bf2f((unsigned short)(v1.y & 0xffff));
        acc8[3] += p1 * bf2f((unsigned short)(v1.y >> 16));
        acc8[4] += p1 * bf2f((unsigned short)(v1.z & 0xffff));
        acc8[5] += p1 * bf2f((unsigned short)(v1.z >> 16));
        acc8[6] += p1 * bf2f((unsigned short)(v1.w & 0xffff));
        acc8[7] += p1 * bf2f((unsigned short)(v1.w >> 16));
        acc8[0] += p2 * bf2f((unsigned short)(v2.x & 0xffff));
        acc8[1] += p2 * bf2f((unsigned short)(v2.x >> 16));
        acc8[2] += p2 * bf2f((unsigned short)(v2.y & 0xffff));
        acc8[3] += p2 * bf2f((unsigned short)(v2.y >> 16));
        acc8[4] += p2 * bf2f((unsigned short)(v2.z & 0xffff));
        acc8[5] += p2 * bf2f((unsigned short)(v2.z >> 16));
        acc8[6] += p2 * bf2f((unsigned short)(v2.w & 0xffff));
        acc8[7] += p2 * bf2f((unsigned short)(v2.w >> 16));
        acc8[0] += p3 * bf2f((unsigned short)(v3.x & 0xffff));
        acc8[1] += p3 * bf2f((unsigned short)(v3.x >> 16));
        acc8[2] += p3 * bf2f((unsigned short)(v3.y & 0xffff));
        acc8[3] += p3 * bf2f((unsigned short)(v3.y >> 16));
        acc8[4] += p3 * bf2f((unsigned short)(v3.z & 0xffff));
        acc8[5] += p3 * bf2f((unsigned short)(v3.z >> 16));
        acc8[6] += p3 * bf2f((unsigned short)(v3.w & 0xffff));
        acc8[7] += p3 * bf2f((unsigned short)(v3.w >> 16));
    }

    // ---- remaining gather blocks (rare: scnt > 32)
    const int gmax4 = (scnt + 31) >> 5;
#pragma unroll 1
    for (int g = 1; g < gmax4; ++g) {
        const int b0 = g * 32 + sub;
        const uint2 f0 = list[b0];
        const uint2 f1 = list[b0 + 8];
        const uint2 f2 = list[b0 + 16];
        const uint2 f3 = list[b0 + 24];
        const uint4 u0 = *(const uint4*)(Vh + (size_t)f0.x * DMODEL + dbase);
        const uint4 u1 = *(const uint4*)(Vh + (size_t)f1.x * DMODEL + dbase);
        const uint4 u2 = *(const uint4*)(Vh + (size_t)f2.x * DMODEL + dbase);
        const uint4 u3 = *(const uint4*)(Vh + (size_t)f3.x * DMODEL + dbase);
        const float p0 = __builtin_bit_cast(float, f0.y);
        const float p1 = __builtin_bit_cast(float, f1.y);
        const float p2 = __builtin_bit_cast(float, f2.y);
        const float p3 = __builtin_bit_cast(float, f3.y);
        acc8[0] += p0 * bf2f((unsigned short)(u0.x & 0xffff));
        acc8[1] += p0 * bf2f((unsigned short)(u0.x >> 16));
        acc8[2] += p0 * bf2f((unsigned short)(u0.y & 0xffff));
        acc8[3] += p0 * bf2f((unsigned short)(u0.y >> 16));
        acc8[4] += p0 * bf2f((unsigned short)(u0.z & 0xffff));
        acc8[5] += p0 * bf2f((unsigned short)(u0.z >> 16));
        acc8[6] += p0 * bf2f((unsigned short)(u0.w & 0xffff));
        acc8[7] += p0 * bf2f((unsigned short)(u0.w >> 16));
        acc8[0] += p1 * bf2f((unsigned short)(u1.x & 0xffff));
        acc8[1] += p1 * bf2f((unsigned short)(u1.x >> 16));
        acc8[2] += p1 * bf2f((unsigned short)(u1.y & 0xffff));
        acc8[3] += p1 * bf2f((unsigned short)(u1.y >> 16));
        acc8[4] += p1 * bf2f((unsigned short)(u1.z & 0xffff));
        acc8[5] += p1 * bf2f((unsigned short)(u1.z >> 16));
        acc8[6] += p1 * bf2f((unsigned short)(u1.w & 0xffff));
        acc8[7] += p1 * bf2f((unsigned short)(u1.w >> 16));
        acc8[0] += p2 * bf2f((unsigned short)(u2.x & 0xffff));
        acc8[1] += p2 * bf2f((unsigned short)(u2.x >> 16));
        acc8[2] += p2 * bf2f((unsigned short)(u2.y & 0xffff));
        acc8[3] += p2 * bf2f((unsigned short)(u2.y >> 16));
        acc8[4] += p2 * bf2f((unsigned short)(u2.z & 0xffff));
        acc8[5] += p2 * bf2f((unsigned short)(u2.z >> 16));
        acc8[6] += p2 * bf2f((unsigned short)(u2.w & 0xffff));
        acc8[7] += p2 * bf2f((unsigned short)(u2.w >> 16));
        acc8[0] += p3 * bf2f((unsigned short)(u3.x & 0xffff));
        acc8[1] += p3 * bf2f((unsigned short)(u3.x >> 16));
        acc8[2] += p3 * bf2f((unsigned short)(u3.y & 0xffff));
        acc8[3] += p3 * bf2f((unsigned short)(u3.y >> 16));
        acc8[4] += p3 * bf2f((unsigned short)(u3.z & 0xffff));
        acc8[5] += p3 * bf2f((unsigned short)(u3.z >> 16));
        acc8[6] += p3 * bf2f((unsigned short)(u3.w & 0xffff));
        acc8[7] += p3 * bf2f((unsigned short)(u3.w >> 16));
    }
    // reduce across the 8 subgroups (stride-8 butterfly)
#pragma unroll
    for (int d = 0; d < 8; ++d) {
        acc8[d] += __shfl_xor(acc8[d], 8, 64);
        acc8[d] += __shfl_xor(acc8[d], 16, 64);
        acc8[d] += __shfl_xor(acc8[d], 32, 64);
    }
    if (lane < 8) {
        union { unsigned short u[8]; uint4 v; } o;
#pragma unroll
        for (int d = 0; d < 8; ++d) o.u[d] = f2bf(acc8[d]);
        *(uint4*)(AO_bf + ((size_t)(b_ * S_LEN + r0 + w)) * DMODEL
                  + h * 64 + lane * 8) = o.v;
    }
}

// ---------------------- out = AO @ Wfc^T + bfc (bf16 A, fp32 W inline-cast)
// Single-barrier double-buffered LDS pipeline (same as qkv).
__global__ __launch_bounds__(256)
void fc_gemm(const unsigned short* __restrict__ AO_bf,
             const float* __restrict__ Wfc,
             const float* __restrict__ bfc, float* __restrict__ out) {
    const int row0 = blockIdx.x * 128;
    const int col0 = blockIdx.y * 128;

    __shared__ unsigned short SMEM[20480];    // 2 x (As 5120 + Bs 5120); 40 KB

    const int t = threadIdx.x;
    const int wid = t >> 6, lane = t & 63;
    const int wm = wid >> 1, wn = wid & 1;
    const int l = lane & 15, quad = lane >> 4;

    f32x4 acc[4][4];
#pragma unroll
    for (int i = 0; i < 4; ++i)
#pragma unroll
        for (int j = 0; j < 4; ++j) {
            float b_ = bfc[col0 + wn * 64 + j * 16 + l];
            acc[i][j] = (f32x4){ b_, b_, b_, b_ };
        }

    uint4 ar[2], br[2];
#pragma unroll
    for (int i = 0; i < 2; ++i) {
        const int c = t + i * 256, r = c >> 2, q = (c & 3) * 8;
        ar[i] = *(const uint4*)(AO_bf + (size_t)(row0 + r) * DMODEL + q);
        const float* wp = Wfc + (size_t)(col0 + r) * DMODEL + q;
        float4 w0 = *(const float4*)wp, w1 = *(const float4*)(wp + 4);
        br[i] = pack8(w0, w1);
    }

    for (int k0 = 0; k0 < DMODEL; k0 += 32) {
        unsigned short* As = SMEM + ((k0 >> 5) & 1) * 10240;
        unsigned short* Bs = As + 5120;
#pragma unroll
        for (int i = 0; i < 2; ++i) {
            const int c = t + i * 256, r = c >> 2, q = (c & 3) * 8;
            *(uint4*)&As[r * 40 + q] = ar[i];
            *(uint4*)&Bs[r * 40 + q] = br[i];
        }
        __syncthreads();
        if (k0 + 32 < DMODEL) {
#pragma unroll
            for (int i = 0; i < 2; ++i) {
                const int c = t + i * 256, r = c >> 2, q = (c & 3) * 8;
                ar[i] = *(const uint4*)(AO_bf + (size_t)(row0 + r) * DMODEL + k0 + 32 + q);
                const float* wp = Wfc + (size_t)(col0 + r) * DMODEL + k0 + 32 + q;
                float4 w0 = *(const float4*)wp, w1 = *(const float4*)(wp + 4);
                br[i] = pack8(w0, w1);
            }
        }
        bf16x8 a[4], b[4];
#pragma unroll
        for (int i = 0; i < 4; ++i)
            a[i] = *(const bf16x8*)&As[(wm * 64 + i * 16 + l) * 40 + quad * 8];
#pragma unroll
        for (int j = 0; j < 4; ++j)
            b[j] = *(const bf16x8*)&Bs[(wn * 64 + j * 16 + l) * 40 + quad * 8];
#pragma unroll
        for (int i = 0; i < 4; ++i)
#pragma unroll
            for (int j = 0; j < 4; ++j)
                acc[i][j] = __builtin_amdgcn_mfma_f32_16x16x32_bf16(a[i], b[j], acc[i][j], 0, 0, 0);
    }

#pragma unroll
    for (int i = 0; i < 4; ++i)
#pragma unroll
        for (int r = 0; r < 4; ++r) {
            const int m = row0 + wm * 64 + i * 16 + quad * 4 + r;
#pragma unroll
            for (int j = 0; j < 4; ++j) {
                const int n = col0 + wn * 64 + j * 16 + l;
                out[(size_t)m * DMODEL + n] = acc[i][j][r];
            }
        }
}

// ----------------------------------------------------------------------- launch
extern "C" void kernel_launch(void* const* d_in, const int* in_sizes, int n_in,
                              void* d_out, int out_size, void* d_ws, size_t ws_size,
                              hipStream_t stream) {
    const float* q   = (const float*)d_in[0];
    const float* k   = (const float*)d_in[1];
    const float* v   = (const float*)d_in[2];
    const float* Wq  = (const float*)d_in[3];
    const float* bq  = (const float*)d_in[4];
    const float* Wk  = (const float*)d_in[5];
    const float* bk  = (const float*)d_in[6];
    const float* Wv  = (const float*)d_in[7];
    const float* bv  = (const float*)d_in[8];
    const float* Wfc = (const float*)d_in[9];
    const float* bfc = (const float*)d_in[10];

    float* out  = (float*)d_out;                       // [B,S,D] fp32
    float* attn = out + (size_t)M_ROWS * DMODEL;       // [B,H,S,S] fp32

    // workspace: Q_bf [0,8M), K_bf [8,16M), V_bf [16,24M), AO_bf [24,32M)
    char* ws = (char*)d_ws;
    unsigned short* Q_bf  = (unsigned short*)ws;
    unsigned short* K_bf  = (unsigned short*)(ws + (8u << 20));
    unsigned short* V_bf  = (unsigned short*)(ws + (16u << 20));
    unsigned short* AO_bf = (unsigned short*)(ws + (24u << 20));

    qkv_gemm<<<dim3(32, 8, 3), 256, 0, stream>>>(q, k, v, Wq, Wk, Wv,
                                                  bq, bk, bv, Q_bf, K_bf, V_bf);
    attn_fused<<<dim3(S_LEN / 16, 32), 1024, 0, stream>>>(Q_bf, K_bf, V_bf, attn, AO_bf);
    fc_gemm<<<dim3(32, 8), 256, 0, stream>>>(AO_bf, Wfc, bfc, out);
}